// Round 1
// baseline (5310.598 us; speedup 1.0000x reference)
//
#include <hip/hip_runtime.h>

// LightGCN-style propagation:
//   3 layers of  new_i = segsum_i(u_h[eu]*w), new_u = segsum_u(i_h[ei]*w)
//   acc += h each layer; out = 0.25*acc gathered at users/pos/neg.
//
// Inputs (order from setup_inputs):
//  0 user_feat f32 [200000,64]
//  1 item_feat f32 [100000,64]
//  2 edge_u    i32 [1000000]
//  3 edge_i    i32 [1000000]
//  4 norm      f32 [1000000]
//  5 users     i32 [8192]
//  6 pos_items i32 [8192]
//  7 neg_items i32 [8192]
// Output: f32 [3*8192*64] concatenated (u_acc[users], i_acc[pos], i_acc[neg]).

#define N_USERS 200000
#define N_ITEMS 100000
#define N_EDGES 1000000
#define DIM 64
#define BATCH 8192

// One edge handled by 16 threads, 4 dims each (float4 gather, 8 fp32 atomics).
__global__ void scatter_kernel(const float* __restrict__ u_h,
                               const float* __restrict__ i_h,
                               const int* __restrict__ eu,
                               const int* __restrict__ ei,
                               const float* __restrict__ w,
                               float* __restrict__ new_u,
                               float* __restrict__ new_i)
{
    int idx = blockIdx.x * blockDim.x + threadIdx.x;
    int e = idx >> 4;
    if (e >= N_EDGES) return;
    int d4 = (idx & 15) << 2;

    int u  = eu[e];
    int it = ei[e];
    float wv = w[e];

    float4 uv = *reinterpret_cast<const float4*>(u_h + (size_t)u  * DIM + d4);
    float4 iv = *reinterpret_cast<const float4*>(i_h + (size_t)it * DIM + d4);

    float* nip = new_i + (size_t)it * DIM + d4;
    float* nup = new_u + (size_t)u  * DIM + d4;

    unsafeAtomicAdd(nip + 0, uv.x * wv);
    unsafeAtomicAdd(nip + 1, uv.y * wv);
    unsafeAtomicAdd(nip + 2, uv.z * wv);
    unsafeAtomicAdd(nip + 3, uv.w * wv);

    unsafeAtomicAdd(nup + 0, iv.x * wv);
    unsafeAtomicAdd(nup + 1, iv.y * wv);
    unsafeAtomicAdd(nup + 2, iv.z * wv);
    unsafeAtomicAdd(nup + 3, iv.w * wv);
}

// acc += delta for both user and item arrays in one launch (float4 lanes).
__global__ void accum_kernel(const float4* __restrict__ du, float4* __restrict__ au,
                             const float4* __restrict__ di, float4* __restrict__ ai)
{
    const int NU4 = N_USERS * DIM / 4;   // 3,200,000
    const int NI4 = N_ITEMS * DIM / 4;   // 1,600,000
    int idx = blockIdx.x * blockDim.x + threadIdx.x;
    if (idx < NU4) {
        float4 a = au[idx];
        float4 d = du[idx];
        a.x += d.x; a.y += d.y; a.z += d.z; a.w += d.w;
        au[idx] = a;
    } else if (idx < NU4 + NI4) {
        int j = idx - NU4;
        float4 a = ai[j];
        float4 d = di[j];
        a.x += d.x; a.y += d.y; a.z += d.z; a.w += d.w;
        ai[j] = a;
    }
}

// out rows 0..8191: uAcc[users], 8192..16383: iAcc[pos], 16384..24575: iAcc[neg]
__global__ void gather_kernel(const float* __restrict__ uAcc,
                              const float* __restrict__ iAcc,
                              const int* __restrict__ users,
                              const int* __restrict__ pos,
                              const int* __restrict__ neg,
                              float* __restrict__ out)
{
    int idx = blockIdx.x * blockDim.x + threadIdx.x;
    int row = idx >> 4;
    if (row >= 3 * BATCH) return;
    int d4 = (idx & 15) << 2;
    int seg = row >> 13;          // 8192 rows per segment
    int b = row & (BATCH - 1);

    const float* src;
    if (seg == 0)      src = uAcc + (size_t)users[b] * DIM;
    else if (seg == 1) src = iAcc + (size_t)pos[b]   * DIM;
    else               src = iAcc + (size_t)neg[b]   * DIM;

    float4 v = *reinterpret_cast<const float4*>(src + d4);
    const float s = 0.25f;  // 1/(NUM_LAYERS+1)
    v.x *= s; v.y *= s; v.z *= s; v.w *= s;
    *reinterpret_cast<float4*>(out + (size_t)row * DIM + d4) = v;
}

extern "C" void kernel_launch(void* const* d_in, const int* in_sizes, int n_in,
                              void* d_out, int out_size, void* d_ws, size_t ws_size,
                              hipStream_t stream)
{
    const float* user_feat = (const float*)d_in[0];
    const float* item_feat = (const float*)d_in[1];
    const int*   eu        = (const int*)d_in[2];
    const int*   ei        = (const int*)d_in[3];
    const float* norm      = (const float*)d_in[4];
    const int*   users     = (const int*)d_in[5];
    const int*   pos       = (const int*)d_in[6];
    const int*   neg       = (const int*)d_in[7];
    float* out = (float*)d_out;

    const size_t uBytes = (size_t)N_USERS * DIM * sizeof(float);   // 51.2 MB
    const size_t iBytes = (size_t)N_ITEMS * DIM * sizeof(float);   // 25.6 MB

    char* p = (char*)d_ws;
    float* uA   = (float*)p; p += uBytes;
    float* uB   = (float*)p; p += uBytes;
    float* uAcc = (float*)p; p += uBytes;
    float* iA   = (float*)p; p += iBytes;
    float* iB   = (float*)p; p += iBytes;
    float* iAcc = (float*)p; p += iBytes;
    // total 230.4 MB of ws used

    // acc = h0
    hipMemcpyAsync(uAcc, user_feat, uBytes, hipMemcpyDeviceToDevice, stream);
    hipMemcpyAsync(iAcc, item_feat, iBytes, hipMemcpyDeviceToDevice, stream);

    const float* cu = user_feat;
    const float* ci = item_feat;
    float* bufU[2] = {uA, uB};
    float* bufI[2] = {iA, iB};

    const int scatterBlocks = (N_EDGES * 16 + 255) / 256;           // 62500
    const int accumBlocks   = ((N_USERS + N_ITEMS) * DIM / 4 + 255) / 256; // 18750

    for (int l = 0; l < 3; ++l) {
        float* nu = bufU[l & 1];
        float* ni = bufI[l & 1];
        hipMemsetAsync(nu, 0, uBytes, stream);
        hipMemsetAsync(ni, 0, iBytes, stream);
        scatter_kernel<<<scatterBlocks, 256, 0, stream>>>(cu, ci, eu, ei, norm, nu, ni);
        accum_kernel<<<accumBlocks, 256, 0, stream>>>(
            (const float4*)nu, (float4*)uAcc, (const float4*)ni, (float4*)iAcc);
        cu = nu;
        ci = ni;
    }

    const int gatherBlocks = (3 * BATCH * 16 + 255) / 256;          // 1536
    gather_kernel<<<gatherBlocks, 256, 0, stream>>>(uAcc, iAcc, users, pos, neg, out);
}

// Round 2
// 898.774 us; speedup vs baseline: 5.9087x; 5.9087x over previous
//
#include <hip/hip_runtime.h>

// LightGCN propagation, CSR-gather formulation (no fp32 atomics).
//
// Per call: build two CSRs (edges grouped by user, edges grouped by item)
// via histogram + exclusive scan + atomic-append fill. Then each layer is
// two gather kernels (one wave per destination row, lane = feature dim),
// with the acc += h update fused in. Final kernel gathers+scales outputs.
//
// Inputs: 0 user_feat f32[200000,64], 1 item_feat f32[100000,64],
//         2 edge_u i32[1M], 3 edge_i i32[1M], 4 norm f32[1M],
//         5 users i32[8192], 6 pos i32[8192], 7 neg i32[8192]
// Output: f32 [3*8192*64] = (u_acc[users], i_acc[pos], i_acc[neg]) * 0.25

#define N_USERS 200000
#define N_ITEMS 100000
#define N_EDGES 1000000
#define DIM 64
#define BATCH 8192
#define NTOT (N_USERS + N_ITEMS)          // 300000 counters (users first)
#define SCAN_CHUNK 1024                   // elems per scan block (256 thr x 4)
#define NBLK ((NTOT + SCAN_CHUNK - 1) / SCAN_CHUNK)   // 293

// ---------------- CSR build ----------------

__global__ void hist_kernel(const int* __restrict__ eu,
                            const int* __restrict__ ei,
                            int* __restrict__ cnt)
{
    int e = blockIdx.x * blockDim.x + threadIdx.x;
    if (e >= N_EDGES) return;
    atomicAdd(&cnt[eu[e]], 1);
    atomicAdd(&cnt[N_USERS + ei[e]], 1);
}

// K1: per-block sums of cnt (1024 elems/block)
__global__ void scan_block_sums(const int* __restrict__ cnt,
                                int* __restrict__ partials, int n)
{
    __shared__ int s[256];
    int t = threadIdx.x;
    int idx = blockIdx.x * SCAN_CHUNK + t * 4;
    int4 v = make_int4(0, 0, 0, 0);
    if (idx < n) v = *reinterpret_cast<const int4*>(cnt + idx);  // n % 4 == 0
    s[t] = v.x + v.y + v.z + v.w;
    __syncthreads();
    for (int off = 128; off > 0; off >>= 1) {
        if (t < off) s[t] += s[t + off];
        __syncthreads();
    }
    if (t == 0) partials[blockIdx.x] = s[0];
}

// K2: single-block exclusive scan of the 293 partials; also writes rp[n].
__global__ void scan_partials_k(int* __restrict__ partials,
                                int* __restrict__ rp, int nb, int n)
{
    __shared__ int s[512];
    int t = threadIdx.x;
    s[t] = (t < nb) ? partials[t] : 0;
    __syncthreads();
    for (int off = 1; off < 512; off <<= 1) {
        int x = (t >= off) ? s[t - off] : 0;
        __syncthreads();
        s[t] += x;
        __syncthreads();
    }
    if (t < nb) partials[t] = (t == 0) ? 0 : s[t - 1];
    if (t == 0) rp[n] = 2 * N_EDGES;
}

// K3: final exclusive scan: local scan + block offset.
__global__ void scan_final(const int* __restrict__ cnt,
                           const int* __restrict__ partials,
                           int* __restrict__ rp, int n)
{
    __shared__ int s[256];
    int t = threadIdx.x;
    int idx = blockIdx.x * SCAN_CHUNK + t * 4;
    int4 v = make_int4(0, 0, 0, 0);
    if (idx < n) v = *reinterpret_cast<const int4*>(cnt + idx);
    int tsum = v.x + v.y + v.z + v.w;
    s[t] = tsum;
    __syncthreads();
    for (int off = 1; off < 256; off <<= 1) {
        int x = (t >= off) ? s[t - off] : 0;
        __syncthreads();
        s[t] += x;
        __syncthreads();
    }
    int base = partials[blockIdx.x] + ((t == 0) ? 0 : s[t - 1]);
    if (idx < n) {
        rp[idx + 0] = base;
        rp[idx + 1] = base + v.x;
        rp[idx + 2] = base + v.x + v.y;
        rp[idx + 3] = base + v.x + v.y + v.z;
    }
}

// Fill CSR entries: user-grouped entry = (item, w), item-grouped = (user, w).
__global__ void fill_kernel(const int* __restrict__ eu,
                            const int* __restrict__ ei,
                            const float* __restrict__ w,
                            int* __restrict__ cursor,
                            int2* __restrict__ entries)
{
    int e = blockIdx.x * blockDim.x + threadIdx.x;
    if (e >= N_EDGES) return;
    int u = eu[e], it = ei[e];
    int wb = __float_as_int(w[e]);
    int pu = atomicAdd(&cursor[u], 1);
    entries[pu] = make_int2(it, wb);
    int pi = atomicAdd(&cursor[N_USERS + it], 1);
    entries[pi] = make_int2(u, wb);
}

// ---------------- aggregation ----------------
// One 64-lane wave per destination row; lane = dim. acc += sum fused.
__global__ void agg_kernel(const int* __restrict__ rp,
                           const int2* __restrict__ entries,
                           const float* __restrict__ src,
                           float* __restrict__ dst,
                           float* __restrict__ acc,
                           int n_rows)
{
    int gid = blockIdx.x * blockDim.x + threadIdx.x;
    int row = gid >> 6;
    int lane = gid & 63;
    if (row >= n_rows) return;
    int beg = rp[row], end = rp[row + 1];
    float sum = 0.f;
    int k = beg;
    for (; k + 1 < end; k += 2) {
        int2 e0 = entries[k];
        int2 e1 = entries[k + 1];
        float a = src[(size_t)e0.x * DIM + lane];
        float b = src[(size_t)e1.x * DIM + lane];
        sum += a * __int_as_float(e0.y);
        sum += b * __int_as_float(e1.y);
    }
    if (k < end) {
        int2 e0 = entries[k];
        sum += src[(size_t)e0.x * DIM + lane] * __int_as_float(e0.y);
    }
    size_t o = (size_t)row * DIM + lane;
    dst[o] = sum;
    acc[o] += sum;
}

// ---------------- output gather ----------------
__global__ void gather_kernel(const float* __restrict__ uAcc,
                              const float* __restrict__ iAcc,
                              const int* __restrict__ users,
                              const int* __restrict__ pos,
                              const int* __restrict__ neg,
                              float* __restrict__ out)
{
    int idx = blockIdx.x * blockDim.x + threadIdx.x;
    int row = idx >> 4;
    if (row >= 3 * BATCH) return;
    int d4 = (idx & 15) << 2;
    int seg = row >> 13;
    int b = row & (BATCH - 1);

    const float* src;
    if (seg == 0)      src = uAcc + (size_t)users[b] * DIM;
    else if (seg == 1) src = iAcc + (size_t)pos[b]   * DIM;
    else               src = iAcc + (size_t)neg[b]   * DIM;

    float4 v = *reinterpret_cast<const float4*>(src + d4);
    const float s = 0.25f;
    v.x *= s; v.y *= s; v.z *= s; v.w *= s;
    *reinterpret_cast<float4*>(out + (size_t)row * DIM + d4) = v;
}

extern "C" void kernel_launch(void* const* d_in, const int* in_sizes, int n_in,
                              void* d_out, int out_size, void* d_ws, size_t ws_size,
                              hipStream_t stream)
{
    const float* user_feat = (const float*)d_in[0];
    const float* item_feat = (const float*)d_in[1];
    const int*   eu        = (const int*)d_in[2];
    const int*   ei        = (const int*)d_in[3];
    const float* norm      = (const float*)d_in[4];
    const int*   users     = (const int*)d_in[5];
    const int*   pos       = (const int*)d_in[6];
    const int*   neg       = (const int*)d_in[7];
    float* out = (float*)d_out;

    const size_t uBytes = (size_t)N_USERS * DIM * sizeof(float);   // 51.2 MB
    const size_t iBytes = (size_t)N_ITEMS * DIM * sizeof(float);   // 25.6 MB
    auto align256 = [](size_t x) { return (x + 255) & ~(size_t)255; };

    char* p = (char*)d_ws;
    float* uA   = (float*)p; p += align256(uBytes);
    float* uB   = (float*)p; p += align256(uBytes);
    float* uAcc = (float*)p; p += align256(uBytes);
    float* iC   = (float*)p; p += align256(iBytes);
    float* iAcc = (float*)p; p += align256(iBytes);
    int*  cnt     = (int*)p;  p += align256((size_t)NTOT * 4);
    int*  rp      = (int*)p;  p += align256((size_t)(NTOT + 1) * 4);
    int*  cursor  = (int*)p;  p += align256((size_t)NTOT * 4);
    int*  partials= (int*)p;  p += align256(512 * 4);
    int2* entries = (int2*)p; p += align256((size_t)2 * N_EDGES * 8);
    // total ~224.5 MB

    // acc = h0
    hipMemcpyAsync(uAcc, user_feat, uBytes, hipMemcpyDeviceToDevice, stream);
    hipMemcpyAsync(iAcc, item_feat, iBytes, hipMemcpyDeviceToDevice, stream);

    // ---- CSR build ----
    hipMemsetAsync(cnt, 0, (size_t)NTOT * 4, stream);
    const int edgeBlocks = (N_EDGES + 255) / 256;
    hist_kernel<<<edgeBlocks, 256, 0, stream>>>(eu, ei, cnt);
    scan_block_sums<<<NBLK, 256, 0, stream>>>(cnt, partials, NTOT);
    scan_partials_k<<<1, 512, 0, stream>>>(partials, rp, NBLK, NTOT);
    scan_final<<<NBLK, 256, 0, stream>>>(cnt, partials, rp, NTOT);
    hipMemcpyAsync(cursor, rp, (size_t)NTOT * 4, hipMemcpyDeviceToDevice, stream);
    fill_kernel<<<edgeBlocks, 256, 0, stream>>>(eu, ei, norm, cursor, entries);

    const int* rp_u = rp;             // offsets into combined `entries`
    const int* rp_i = rp + N_USERS;

    const int uAggBlocks = (N_USERS * 64 + 255) / 256;   // 50000
    const int iAggBlocks = (N_ITEMS * 64 + 255) / 256;   // 25000

    // ---- layer 0: reads const inputs ----
    agg_kernel<<<uAggBlocks, 256, 0, stream>>>(rp_u, entries, item_feat, uA, uAcc, N_USERS);
    agg_kernel<<<iAggBlocks, 256, 0, stream>>>(rp_i, entries, user_feat, iC, iAcc, N_ITEMS);
    // ---- layer 1: u: uA->uB, i: iC->iC in place (users kernel consumed iC first) ----
    agg_kernel<<<uAggBlocks, 256, 0, stream>>>(rp_u, entries, iC, uB, uAcc, N_USERS);
    agg_kernel<<<iAggBlocks, 256, 0, stream>>>(rp_i, entries, uA, iC, iAcc, N_ITEMS);
    // ---- layer 2 ----
    agg_kernel<<<uAggBlocks, 256, 0, stream>>>(rp_u, entries, iC, uA, uAcc, N_USERS);
    agg_kernel<<<iAggBlocks, 256, 0, stream>>>(rp_i, entries, uB, iC, iAcc, N_ITEMS);

    const int gatherBlocks = (3 * BATCH * 16 + 255) / 256;
    gather_kernel<<<gatherBlocks, 256, 0, stream>>>(uAcc, iAcc, users, pos, neg, out);
}

// Round 3
// 740.577 us; speedup vs baseline: 7.1709x; 1.2136x over previous
//
#include <hip/hip_runtime.h>

// LightGCN propagation, CSR-gather formulation, acc-free.
//
// CSR build (hist + scan + atomic-append fill) each call, then per layer one
// merged gather kernel (users+items, one wave per destination row, lane=dim,
// cooperative entry load + shfl broadcast). Layer outputs are accumulated
// directly into d_out at the 3*8192 gathered rows (no full-size acc arrays).
//
// Inputs: 0 user_feat f32[200000,64], 1 item_feat f32[100000,64],
//         2 edge_u i32[1M], 3 edge_i i32[1M], 4 norm f32[1M],
//         5 users i32[8192], 6 pos i32[8192], 7 neg i32[8192]
// Output: f32 [3*8192*64] = (u_acc[users], i_acc[pos], i_acc[neg]) * 0.25

#define N_USERS 200000
#define N_ITEMS 100000
#define N_EDGES 1000000
#define DIM 64
#define BATCH 8192
#define NTOT (N_USERS + N_ITEMS)          // 300000 rows (users first)
#define SCAN_CHUNK 1024
#define NBLK ((NTOT + SCAN_CHUNK - 1) / SCAN_CHUNK)   // 293

// ---------------- CSR build ----------------

__global__ void hist_kernel(const int* __restrict__ eu,
                            const int* __restrict__ ei,
                            int* __restrict__ cnt)
{
    int e0 = (blockIdx.x * blockDim.x + threadIdx.x) * 2;
    if (e0 >= N_EDGES) return;
    int u0 = eu[e0], u1 = eu[e0 + 1];
    int i0 = ei[e0], i1 = ei[e0 + 1];
    atomicAdd(&cnt[u0], 1);
    atomicAdd(&cnt[N_USERS + i0], 1);
    atomicAdd(&cnt[u1], 1);
    atomicAdd(&cnt[N_USERS + i1], 1);
}

__global__ void scan_block_sums(const int* __restrict__ cnt,
                                int* __restrict__ partials, int n)
{
    __shared__ int s[256];
    int t = threadIdx.x;
    int idx = blockIdx.x * SCAN_CHUNK + t * 4;
    int4 v = make_int4(0, 0, 0, 0);
    if (idx < n) v = *reinterpret_cast<const int4*>(cnt + idx);
    s[t] = v.x + v.y + v.z + v.w;
    __syncthreads();
    for (int off = 128; off > 0; off >>= 1) {
        if (t < off) s[t] += s[t + off];
        __syncthreads();
    }
    if (t == 0) partials[blockIdx.x] = s[0];
}

__global__ void scan_partials_k(int* __restrict__ partials,
                                int* __restrict__ rp, int nb, int n)
{
    __shared__ int s[512];
    int t = threadIdx.x;
    s[t] = (t < nb) ? partials[t] : 0;
    __syncthreads();
    for (int off = 1; off < 512; off <<= 1) {
        int x = (t >= off) ? s[t - off] : 0;
        __syncthreads();
        s[t] += x;
        __syncthreads();
    }
    if (t < nb) partials[t] = (t == 0) ? 0 : s[t - 1];
    if (t == 0) rp[n] = 2 * N_EDGES;
}

__global__ void scan_final(const int* __restrict__ cnt,
                           const int* __restrict__ partials,
                           int* __restrict__ rp, int n)
{
    __shared__ int s[256];
    int t = threadIdx.x;
    int idx = blockIdx.x * SCAN_CHUNK + t * 4;
    int4 v = make_int4(0, 0, 0, 0);
    if (idx < n) v = *reinterpret_cast<const int4*>(cnt + idx);
    int tsum = v.x + v.y + v.z + v.w;
    s[t] = tsum;
    __syncthreads();
    for (int off = 1; off < 256; off <<= 1) {
        int x = (t >= off) ? s[t - off] : 0;
        __syncthreads();
        s[t] += x;
        __syncthreads();
    }
    int base = partials[blockIdx.x] + ((t == 0) ? 0 : s[t - 1]);
    if (idx < n) {
        rp[idx + 0] = base;
        rp[idx + 1] = base + v.x;
        rp[idx + 2] = base + v.x + v.y;
        rp[idx + 3] = base + v.x + v.y + v.z;
    }
}

// 2 edges/thread; all 4 atomics issued before the 4 dependent stores.
__global__ void fill_kernel(const int* __restrict__ eu,
                            const int* __restrict__ ei,
                            const float* __restrict__ w,
                            int* __restrict__ cursor,
                            int2* __restrict__ entries)
{
    int e0 = (blockIdx.x * blockDim.x + threadIdx.x) * 2;
    if (e0 >= N_EDGES) return;
    int u0 = eu[e0], u1 = eu[e0 + 1];
    int i0 = ei[e0], i1 = ei[e0 + 1];
    int w0 = __float_as_int(w[e0]);
    int w1 = __float_as_int(w[e0 + 1]);
    int pu0 = atomicAdd(&cursor[u0], 1);
    int pi0 = atomicAdd(&cursor[N_USERS + i0], 1);
    int pu1 = atomicAdd(&cursor[u1], 1);
    int pi1 = atomicAdd(&cursor[N_USERS + i1], 1);
    entries[pu0] = make_int2(i0, w0);
    entries[pi0] = make_int2(u0, w0);
    entries[pu1] = make_int2(i1, w1);
    entries[pi1] = make_int2(u1, w1);
}

// ---------------- merged aggregation ----------------
// One 64-lane wave per destination row (users then items). Entry list loaded
// cooperatively (one lane per entry) and broadcast via shfl, so the inner
// loop's only memory op is the 256B coalesced feature-row gather.
__global__ void agg_kernel(const int* __restrict__ rp,
                           const int2* __restrict__ entries,
                           const float* __restrict__ src_u,
                           const float* __restrict__ src_i,
                           float* __restrict__ dst_u,
                           float* __restrict__ dst_i)
{
    int gid = blockIdx.x * blockDim.x + threadIdx.x;
    int row = gid >> 6;
    int lane = gid & 63;
    if (row >= NTOT) return;
    int beg = rp[row], end = rp[row + 1];
    int cnt = end - beg;
    const float* __restrict__ src = (row < N_USERS) ? src_i : src_u;

    int2 e = make_int2(0, 0);
    if (lane < cnt) e = entries[beg + lane];

    float s0 = 0.f, s1 = 0.f;
    int m = min(cnt, 64);
    int j = 0;
    for (; j + 1 < m; j += 2) {
        int c0 = __shfl(e.x, j);     int w0 = __shfl(e.y, j);
        int c1 = __shfl(e.x, j + 1); int w1 = __shfl(e.y, j + 1);
        s0 += src[(size_t)c0 * DIM + lane] * __int_as_float(w0);
        s1 += src[(size_t)c1 * DIM + lane] * __int_as_float(w1);
    }
    if (j < m) {
        int c0 = __shfl(e.x, j); int w0 = __shfl(e.y, j);
        s0 += src[(size_t)c0 * DIM + lane] * __int_as_float(w0);
    }
    for (int k = beg + 64; k < end; ++k) {   // degree>64: effectively never
        int2 et = entries[k];
        s0 += src[(size_t)et.x * DIM + lane] * __int_as_float(et.y);
    }
    float sum = s0 + s1;
    if (row < N_USERS) dst_u[(size_t)row * DIM + lane] = sum;
    else               dst_i[(size_t)(row - N_USERS) * DIM + lane] = sum;
}

// ---------------- output init / accumulate ----------------
// out rows 0..8191: users from u_src; 8192..16383: pos from i_src;
// 16384..24575: neg from i_src. out (+)= 0.25 * gather.
template <bool ADD>
__global__ void out_accum_kernel(const float* __restrict__ u_src,
                                 const float* __restrict__ i_src,
                                 const int* __restrict__ users,
                                 const int* __restrict__ pos,
                                 const int* __restrict__ neg,
                                 float* __restrict__ out)
{
    int idx = blockIdx.x * blockDim.x + threadIdx.x;
    int row = idx >> 4;
    if (row >= 3 * BATCH) return;
    int d4 = (idx & 15) << 2;
    int seg = row >> 13;
    int b = row & (BATCH - 1);

    const float* src;
    if (seg == 0)      src = u_src + (size_t)users[b] * DIM;
    else if (seg == 1) src = i_src + (size_t)pos[b]   * DIM;
    else               src = i_src + (size_t)neg[b]   * DIM;

    float4 v = *reinterpret_cast<const float4*>(src + d4);
    const float s = 0.25f;
    float* op = out + (size_t)row * DIM + d4;
    if (ADD) {
        float4 o = *reinterpret_cast<const float4*>(op);
        v.x = o.x + v.x * s; v.y = o.y + v.y * s;
        v.z = o.z + v.z * s; v.w = o.w + v.w * s;
    } else {
        v.x *= s; v.y *= s; v.z *= s; v.w *= s;
    }
    *reinterpret_cast<float4*>(op) = v;
}

extern "C" void kernel_launch(void* const* d_in, const int* in_sizes, int n_in,
                              void* d_out, int out_size, void* d_ws, size_t ws_size,
                              hipStream_t stream)
{
    const float* user_feat = (const float*)d_in[0];
    const float* item_feat = (const float*)d_in[1];
    const int*   eu        = (const int*)d_in[2];
    const int*   ei        = (const int*)d_in[3];
    const float* norm      = (const float*)d_in[4];
    const int*   users     = (const int*)d_in[5];
    const int*   pos       = (const int*)d_in[6];
    const int*   neg       = (const int*)d_in[7];
    float* out = (float*)d_out;

    const size_t uBytes = (size_t)N_USERS * DIM * sizeof(float);   // 51.2 MB
    const size_t iBytes = (size_t)N_ITEMS * DIM * sizeof(float);   // 25.6 MB
    auto align256 = [](size_t x) { return (x + 255) & ~(size_t)255; };

    char* p = (char*)d_ws;
    float* uA = (float*)p; p += align256(uBytes);
    float* uB = (float*)p; p += align256(uBytes);
    float* iA = (float*)p; p += align256(iBytes);
    float* iB = (float*)p; p += align256(iBytes);
    int*  cnt      = (int*)p;  p += align256((size_t)NTOT * 4);
    int*  rp       = (int*)p;  p += align256((size_t)(NTOT + 1) * 4);
    int*  cursor   = (int*)p;  p += align256((size_t)NTOT * 4);
    int*  partials = (int*)p;  p += align256(512 * 4);
    int2* entries  = (int2*)p; p += align256((size_t)2 * N_EDGES * 8);
    // total ~173.4 MB

    // ---- CSR build ----
    hipMemsetAsync(cnt, 0, (size_t)NTOT * 4, stream);
    const int edgeBlocks2 = (N_EDGES / 2 + 255) / 256;
    hist_kernel<<<edgeBlocks2, 256, 0, stream>>>(eu, ei, cnt);
    scan_block_sums<<<NBLK, 256, 0, stream>>>(cnt, partials, NTOT);
    scan_partials_k<<<1, 512, 0, stream>>>(partials, rp, NBLK, NTOT);
    scan_final<<<NBLK, 256, 0, stream>>>(cnt, partials, rp, NTOT);
    hipMemcpyAsync(cursor, rp, (size_t)NTOT * 4, hipMemcpyDeviceToDevice, stream);
    fill_kernel<<<edgeBlocks2, 256, 0, stream>>>(eu, ei, norm, cursor, entries);

    const int aggBlocks = (NTOT * 64 + 255) / 256;           // 75000
    const int outBlocks = (3 * BATCH * 16 + 255) / 256;      // 1536

    // out = 0.25 * h0 at gathered rows
    out_accum_kernel<false><<<outBlocks, 256, 0, stream>>>(
        user_feat, item_feat, users, pos, neg, out);

    // layer 1
    agg_kernel<<<aggBlocks, 256, 0, stream>>>(rp, entries, user_feat, item_feat, uA, iA);
    out_accum_kernel<true><<<outBlocks, 256, 0, stream>>>(uA, iA, users, pos, neg, out);
    // layer 2
    agg_kernel<<<aggBlocks, 256, 0, stream>>>(rp, entries, uA, iA, uB, iB);
    out_accum_kernel<true><<<outBlocks, 256, 0, stream>>>(uB, iB, users, pos, neg, out);
    // layer 3
    agg_kernel<<<aggBlocks, 256, 0, stream>>>(rp, entries, uB, iB, uA, iA);
    out_accum_kernel<true><<<outBlocks, 256, 0, stream>>>(uA, iA, users, pos, neg, out);
}

// Round 4
// 515.665 us; speedup vs baseline: 10.2986x; 1.4362x over previous
//
#include <hip/hip_runtime.h>

// LightGCN propagation, CSR-gather formulation, acc-free, atomic-free fill,
// pruned final layer.
//
// Pipeline per call:
//   1. hist_rank: cnt[row]++ via atomicAdd, returned old value = edge's rank
//      within its bucket (stored coalesced to ru/ri).
//   2. exclusive scan of cnt -> rp.
//   3. fill: entry slot = rp[row] + rank. No atomics; independent stores.
//   4. layers 1,2: merged gather kernel over all 300K rows (wave per row).
//   5. layer 3 computed ONLY at the 3*8192 output rows, fused with out+=.
//   Layer contributions h0,h1,h2 accumulated into d_out by a tiny kernel.
//
// Inputs: 0 user_feat f32[200000,64], 1 item_feat f32[100000,64],
//         2 edge_u i32[1M], 3 edge_i i32[1M], 4 norm f32[1M],
//         5 users i32[8192], 6 pos i32[8192], 7 neg i32[8192]
// Output: f32 [3*8192*64] = (u_acc[users], i_acc[pos], i_acc[neg]) * 0.25

#define N_USERS 200000
#define N_ITEMS 100000
#define N_EDGES 1000000
#define DIM 64
#define BATCH 8192
#define NTOT (N_USERS + N_ITEMS)          // 300000 rows (users first)
#define SCAN_CHUNK 1024
#define NBLK ((NTOT + SCAN_CHUNK - 1) / SCAN_CHUNK)   // 293

// ---------------- CSR build ----------------

// Histogram + rank: atomicAdd returns this edge's slot-rank in its bucket.
// Rank stores are coalesced (edge order); atomic latency hidden by occupancy.
__global__ void hist_rank_kernel(const int* __restrict__ eu,
                                 const int* __restrict__ ei,
                                 int* __restrict__ cnt,
                                 int* __restrict__ ru,
                                 int* __restrict__ ri)
{
    int e0 = (blockIdx.x * blockDim.x + threadIdx.x) * 2;
    if (e0 >= N_EDGES) return;
    int u0 = eu[e0], u1 = eu[e0 + 1];
    int i0 = ei[e0], i1 = ei[e0 + 1];
    int r0 = atomicAdd(&cnt[u0], 1);
    int r1 = atomicAdd(&cnt[N_USERS + i0], 1);
    int r2 = atomicAdd(&cnt[u1], 1);
    int r3 = atomicAdd(&cnt[N_USERS + i1], 1);
    ru[e0]     = r0;
    ri[e0]     = r1;
    ru[e0 + 1] = r2;
    ri[e0 + 1] = r3;
}

__global__ void scan_block_sums(const int* __restrict__ cnt,
                                int* __restrict__ partials, int n)
{
    __shared__ int s[256];
    int t = threadIdx.x;
    int idx = blockIdx.x * SCAN_CHUNK + t * 4;
    int4 v = make_int4(0, 0, 0, 0);
    if (idx < n) v = *reinterpret_cast<const int4*>(cnt + idx);
    s[t] = v.x + v.y + v.z + v.w;
    __syncthreads();
    for (int off = 128; off > 0; off >>= 1) {
        if (t < off) s[t] += s[t + off];
        __syncthreads();
    }
    if (t == 0) partials[blockIdx.x] = s[0];
}

__global__ void scan_partials_k(int* __restrict__ partials,
                                int* __restrict__ rp, int nb, int n)
{
    __shared__ int s[512];
    int t = threadIdx.x;
    s[t] = (t < nb) ? partials[t] : 0;
    __syncthreads();
    for (int off = 1; off < 512; off <<= 1) {
        int x = (t >= off) ? s[t - off] : 0;
        __syncthreads();
        s[t] += x;
        __syncthreads();
    }
    if (t < nb) partials[t] = (t == 0) ? 0 : s[t - 1];
    if (t == 0) rp[n] = 2 * N_EDGES;
}

__global__ void scan_final(const int* __restrict__ cnt,
                           const int* __restrict__ partials,
                           int* __restrict__ rp, int n)
{
    __shared__ int s[256];
    int t = threadIdx.x;
    int idx = blockIdx.x * SCAN_CHUNK + t * 4;
    int4 v = make_int4(0, 0, 0, 0);
    if (idx < n) v = *reinterpret_cast<const int4*>(cnt + idx);
    int tsum = v.x + v.y + v.z + v.w;
    s[t] = tsum;
    __syncthreads();
    for (int off = 1; off < 256; off <<= 1) {
        int x = (t >= off) ? s[t - off] : 0;
        __syncthreads();
        s[t] += x;
        __syncthreads();
    }
    int base = partials[blockIdx.x] + ((t == 0) ? 0 : s[t - 1]);
    if (idx < n) {
        rp[idx + 0] = base;
        rp[idx + 1] = base + v.x;
        rp[idx + 2] = base + v.x + v.y;
        rp[idx + 3] = base + v.x + v.y + v.z;
    }
}

// Atomic-free fill: slot = rp[bucket] + precomputed rank. All 4 stores are
// independent fire-and-forget scatters.
__global__ void fill_kernel(const int* __restrict__ eu,
                            const int* __restrict__ ei,
                            const float* __restrict__ w,
                            const int* __restrict__ rp,
                            const int* __restrict__ ru,
                            const int* __restrict__ ri,
                            int2* __restrict__ entries)
{
    int e0 = (blockIdx.x * blockDim.x + threadIdx.x) * 2;
    if (e0 >= N_EDGES) return;
    int u0 = eu[e0], u1 = eu[e0 + 1];
    int i0 = ei[e0], i1 = ei[e0 + 1];
    int w0 = __float_as_int(w[e0]);
    int w1 = __float_as_int(w[e0 + 1]);
    int su0 = rp[u0] + ru[e0];
    int si0 = rp[N_USERS + i0] + ri[e0];
    int su1 = rp[u1] + ru[e0 + 1];
    int si1 = rp[N_USERS + i1] + ri[e0 + 1];
    entries[su0] = make_int2(i0, w0);
    entries[si0] = make_int2(u0, w0);
    entries[su1] = make_int2(i1, w1);
    entries[si1] = make_int2(u1, w1);
}

// ---------------- merged aggregation (layers 1,2) ----------------
// One 64-lane wave per destination row (users then items). Entry list loaded
// cooperatively (one lane per entry) and broadcast via shfl.
__global__ void agg_kernel(const int* __restrict__ rp,
                           const int2* __restrict__ entries,
                           const float* __restrict__ src_u,
                           const float* __restrict__ src_i,
                           float* __restrict__ dst_u,
                           float* __restrict__ dst_i)
{
    int gid = blockIdx.x * blockDim.x + threadIdx.x;
    int row = gid >> 6;
    int lane = gid & 63;
    if (row >= NTOT) return;
    int beg = rp[row], end = rp[row + 1];
    int cnt = end - beg;
    const float* __restrict__ src = (row < N_USERS) ? src_i : src_u;

    int2 e = make_int2(0, 0);
    if (lane < cnt) e = entries[beg + lane];

    float s0 = 0.f, s1 = 0.f;
    int m = min(cnt, 64);
    int j = 0;
    for (; j + 1 < m; j += 2) {
        int c0 = __shfl(e.x, j);     int w0 = __shfl(e.y, j);
        int c1 = __shfl(e.x, j + 1); int w1 = __shfl(e.y, j + 1);
        s0 += src[(size_t)c0 * DIM + lane] * __int_as_float(w0);
        s1 += src[(size_t)c1 * DIM + lane] * __int_as_float(w1);
    }
    if (j < m) {
        int c0 = __shfl(e.x, j); int w0 = __shfl(e.y, j);
        s0 += src[(size_t)c0 * DIM + lane] * __int_as_float(w0);
    }
    for (int k = beg + 64; k < end; ++k) {   // degree>64: effectively never
        int2 et = entries[k];
        s0 += src[(size_t)et.x * DIM + lane] * __int_as_float(et.y);
    }
    float sum = s0 + s1;
    if (row < N_USERS) dst_u[(size_t)row * DIM + lane] = sum;
    else               dst_i[(size_t)(row - N_USERS) * DIM + lane] = sum;
}

// ---------------- final layer, output rows only ----------------
// Computes h3 only where it's consumed: out[r] += 0.25 * segsum(h2 gather).
// src_u/src_i are h2. One wave per output row (3*8192 rows).
__global__ void agg_out_kernel(const int* __restrict__ rp,
                               const int2* __restrict__ entries,
                               const float* __restrict__ src_u,
                               const float* __restrict__ src_i,
                               const int* __restrict__ users,
                               const int* __restrict__ pos,
                               const int* __restrict__ neg,
                               float* __restrict__ out)
{
    int gid = blockIdx.x * blockDim.x + threadIdx.x;
    int row = gid >> 6;
    int lane = gid & 63;
    if (row >= 3 * BATCH) return;
    int seg = row >> 13;
    int b = row & (BATCH - 1);

    int bucket;
    const float* __restrict__ src;
    if (seg == 0)      { bucket = users[b];           src = src_i; }
    else if (seg == 1) { bucket = N_USERS + pos[b];   src = src_u; }
    else               { bucket = N_USERS + neg[b];   src = src_u; }

    int beg = rp[bucket], end = rp[bucket + 1];
    int cnt = end - beg;

    int2 e = make_int2(0, 0);
    if (lane < cnt) e = entries[beg + lane];

    float s0 = 0.f, s1 = 0.f;
    int m = min(cnt, 64);
    int j = 0;
    for (; j + 1 < m; j += 2) {
        int c0 = __shfl(e.x, j);     int w0 = __shfl(e.y, j);
        int c1 = __shfl(e.x, j + 1); int w1 = __shfl(e.y, j + 1);
        s0 += src[(size_t)c0 * DIM + lane] * __int_as_float(w0);
        s1 += src[(size_t)c1 * DIM + lane] * __int_as_float(w1);
    }
    if (j < m) {
        int c0 = __shfl(e.x, j); int w0 = __shfl(e.y, j);
        s0 += src[(size_t)c0 * DIM + lane] * __int_as_float(w0);
    }
    for (int k = beg + 64; k < end; ++k) {
        int2 et = entries[k];
        s0 += src[(size_t)et.x * DIM + lane] * __int_as_float(et.y);
    }
    size_t o = (size_t)row * DIM + lane;
    out[o] += 0.25f * (s0 + s1);
}

// ---------------- output init / accumulate (h0, h1, h2) ----------------
template <bool ADD>
__global__ void out_accum_kernel(const float* __restrict__ u_src,
                                 const float* __restrict__ i_src,
                                 const int* __restrict__ users,
                                 const int* __restrict__ pos,
                                 const int* __restrict__ neg,
                                 float* __restrict__ out)
{
    int idx = blockIdx.x * blockDim.x + threadIdx.x;
    int row = idx >> 4;
    if (row >= 3 * BATCH) return;
    int d4 = (idx & 15) << 2;
    int seg = row >> 13;
    int b = row & (BATCH - 1);

    const float* src;
    if (seg == 0)      src = u_src + (size_t)users[b] * DIM;
    else if (seg == 1) src = i_src + (size_t)pos[b]   * DIM;
    else               src = i_src + (size_t)neg[b]   * DIM;

    float4 v = *reinterpret_cast<const float4*>(src + d4);
    const float s = 0.25f;
    float* op = out + (size_t)row * DIM + d4;
    if (ADD) {
        float4 o = *reinterpret_cast<const float4*>(op);
        v.x = o.x + v.x * s; v.y = o.y + v.y * s;
        v.z = o.z + v.z * s; v.w = o.w + v.w * s;
    } else {
        v.x *= s; v.y *= s; v.z *= s; v.w *= s;
    }
    *reinterpret_cast<float4*>(op) = v;
}

extern "C" void kernel_launch(void* const* d_in, const int* in_sizes, int n_in,
                              void* d_out, int out_size, void* d_ws, size_t ws_size,
                              hipStream_t stream)
{
    const float* user_feat = (const float*)d_in[0];
    const float* item_feat = (const float*)d_in[1];
    const int*   eu        = (const int*)d_in[2];
    const int*   ei        = (const int*)d_in[3];
    const float* norm      = (const float*)d_in[4];
    const int*   users     = (const int*)d_in[5];
    const int*   pos       = (const int*)d_in[6];
    const int*   neg       = (const int*)d_in[7];
    float* out = (float*)d_out;

    const size_t uBytes = (size_t)N_USERS * DIM * sizeof(float);   // 51.2 MB
    const size_t iBytes = (size_t)N_ITEMS * DIM * sizeof(float);   // 25.6 MB
    auto align256 = [](size_t x) { return (x + 255) & ~(size_t)255; };

    char* p = (char*)d_ws;
    float* uA = (float*)p; p += align256(uBytes);
    float* uB = (float*)p; p += align256(uBytes);
    float* iA = (float*)p; p += align256(iBytes);
    float* iB = (float*)p; p += align256(iBytes);
    int*  cnt      = (int*)p;  p += align256((size_t)NTOT * 4);
    int*  rp       = (int*)p;  p += align256((size_t)(NTOT + 1) * 4);
    int*  partials = (int*)p;  p += align256(512 * 4);
    int*  ru       = (int*)p;  p += align256((size_t)N_EDGES * 4);
    int*  ri       = (int*)p;  p += align256((size_t)N_EDGES * 4);
    int2* entries  = (int2*)p; p += align256((size_t)2 * N_EDGES * 8);
    // total ~181 MB

    // ---- CSR build ----
    hipMemsetAsync(cnt, 0, (size_t)NTOT * 4, stream);
    const int edgeBlocks2 = (N_EDGES / 2 + 255) / 256;
    hist_rank_kernel<<<edgeBlocks2, 256, 0, stream>>>(eu, ei, cnt, ru, ri);
    scan_block_sums<<<NBLK, 256, 0, stream>>>(cnt, partials, NTOT);
    scan_partials_k<<<1, 512, 0, stream>>>(partials, rp, NBLK, NTOT);
    scan_final<<<NBLK, 256, 0, stream>>>(cnt, partials, rp, NTOT);
    fill_kernel<<<edgeBlocks2, 256, 0, stream>>>(eu, ei, norm, rp, ru, ri, entries);

    const int aggBlocks = (NTOT * 64 + 255) / 256;           // 75000
    const int outBlocks = (3 * BATCH * 16 + 255) / 256;      // 1536
    const int aggOutBlocks = (3 * BATCH * 64 + 255) / 256;   // 6144

    // out = 0.25 * h0 at gathered rows
    out_accum_kernel<false><<<outBlocks, 256, 0, stream>>>(
        user_feat, item_feat, users, pos, neg, out);

    // layer 1 (full)
    agg_kernel<<<aggBlocks, 256, 0, stream>>>(rp, entries, user_feat, item_feat, uA, iA);
    out_accum_kernel<true><<<outBlocks, 256, 0, stream>>>(uA, iA, users, pos, neg, out);
    // layer 2 (full)
    agg_kernel<<<aggBlocks, 256, 0, stream>>>(rp, entries, uA, iA, uB, iB);
    out_accum_kernel<true><<<outBlocks, 256, 0, stream>>>(uB, iB, users, pos, neg, out);
    // layer 3: only at output rows, fused with out +=
    agg_out_kernel<<<aggOutBlocks, 256, 0, stream>>>(
        rp, entries, uB, iB, users, pos, neg, out);
}

// Round 5
// 385.927 us; speedup vs baseline: 13.7606x; 1.3362x over previous
//
#include <hip/hip_runtime.h>

// LightGCN propagation, CSR-gather, bf16 intermediates, unified row space.
//
// Rows 0..199999 = users, 200000..299999 = items. CSR entries store the
// GLOBAL opposite-side row id, so every layer is the same unified gather:
//   H_next[row][d] = sum_{(c,w) in row's bucket} H_prev[c][d] * w
// Feature arrays F0 (converted inputs), H1, H2 are bf16 [300000][64]
// (halves gather bytes + working set; f32 accumulate keeps precision).
// Layer 3 is computed only at the 3*8192 output rows, fused with out +=.
//
// agg layout: 4 rows per wave (quad = 16 lanes, 4 dims/lane), entries
// prefetched cooperatively per 16-chunk + shfl broadcast, 4-deep unrolled
// gathers (4 x 128B independent loads in flight per wave iteration).

#define N_USERS 200000
#define N_ITEMS 100000
#define N_EDGES 1000000
#define DIM 64
#define BATCH 8192
#define NTOT (N_USERS + N_ITEMS)          // 300000 rows
#define SCAN_CHUNK 1024
#define NBLK ((NTOT + SCAN_CHUNK - 1) / SCAN_CHUNK)   // 293

// ---------- bf16 helpers ----------
__device__ __forceinline__ unsigned f2bf(float f) {   // round-to-nearest-even
    unsigned u = __float_as_uint(f);
    return (u + 0x7fffu + ((u >> 16) & 1u)) >> 16;
}
__device__ __forceinline__ uint2 pack4(float4 v) {
    uint2 o;
    o.x = f2bf(v.x) | (f2bf(v.y) << 16);
    o.y = f2bf(v.z) | (f2bf(v.w) << 16);
    return o;
}
__device__ __forceinline__ void fma4(float4& a, uint2 v, float w) {
    a.x += __uint_as_float(v.x << 16) * w;
    a.y += __uint_as_float(v.x & 0xffff0000u) * w;
    a.z += __uint_as_float(v.y << 16) * w;
    a.w += __uint_as_float(v.y & 0xffff0000u) * w;
}

// ---------------- CSR build ----------------

__global__ void hist_rank_kernel(const int* __restrict__ eu,
                                 const int* __restrict__ ei,
                                 int* __restrict__ cnt,
                                 int* __restrict__ ru,
                                 int* __restrict__ ri)
{
    int e0 = (blockIdx.x * blockDim.x + threadIdx.x) * 2;
    if (e0 >= N_EDGES) return;
    int u0 = eu[e0], u1 = eu[e0 + 1];
    int i0 = ei[e0], i1 = ei[e0 + 1];
    int r0 = atomicAdd(&cnt[u0], 1);
    int r1 = atomicAdd(&cnt[N_USERS + i0], 1);
    int r2 = atomicAdd(&cnt[u1], 1);
    int r3 = atomicAdd(&cnt[N_USERS + i1], 1);
    ru[e0]     = r0;
    ri[e0]     = r1;
    ru[e0 + 1] = r2;
    ri[e0 + 1] = r3;
}

__global__ void scan_block_sums(const int* __restrict__ cnt,
                                int* __restrict__ partials, int n)
{
    __shared__ int s[256];
    int t = threadIdx.x;
    int idx = blockIdx.x * SCAN_CHUNK + t * 4;
    int4 v = make_int4(0, 0, 0, 0);
    if (idx < n) v = *reinterpret_cast<const int4*>(cnt + idx);
    s[t] = v.x + v.y + v.z + v.w;
    __syncthreads();
    for (int off = 128; off > 0; off >>= 1) {
        if (t < off) s[t] += s[t + off];
        __syncthreads();
    }
    if (t == 0) partials[blockIdx.x] = s[0];
}

__global__ void scan_partials_k(int* __restrict__ partials,
                                int* __restrict__ rp, int nb, int n)
{
    __shared__ int s[512];
    int t = threadIdx.x;
    s[t] = (t < nb) ? partials[t] : 0;
    __syncthreads();
    for (int off = 1; off < 512; off <<= 1) {
        int x = (t >= off) ? s[t - off] : 0;
        __syncthreads();
        s[t] += x;
        __syncthreads();
    }
    if (t < nb) partials[t] = (t == 0) ? 0 : s[t - 1];
    if (t == 0) rp[n] = 2 * N_EDGES;
}

__global__ void scan_final(const int* __restrict__ cnt,
                           const int* __restrict__ partials,
                           int* __restrict__ rp, int n)
{
    __shared__ int s[256];
    int t = threadIdx.x;
    int idx = blockIdx.x * SCAN_CHUNK + t * 4;
    int4 v = make_int4(0, 0, 0, 0);
    if (idx < n) v = *reinterpret_cast<const int4*>(cnt + idx);
    int tsum = v.x + v.y + v.z + v.w;
    s[t] = tsum;
    __syncthreads();
    for (int off = 1; off < 256; off <<= 1) {
        int x = (t >= off) ? s[t - off] : 0;
        __syncthreads();
        s[t] += x;
        __syncthreads();
    }
    int base = partials[blockIdx.x] + ((t == 0) ? 0 : s[t - 1]);
    if (idx < n) {
        rp[idx + 0] = base;
        rp[idx + 1] = base + v.x;
        rp[idx + 2] = base + v.x + v.y;
        rp[idx + 3] = base + v.x + v.y + v.z;
    }
}

// Atomic-free fill; cols stored as GLOBAL row ids (opposite side).
__global__ void fill_kernel(const int* __restrict__ eu,
                            const int* __restrict__ ei,
                            const float* __restrict__ w,
                            const int* __restrict__ rp,
                            const int* __restrict__ ru,
                            const int* __restrict__ ri,
                            int2* __restrict__ entries)
{
    int e0 = (blockIdx.x * blockDim.x + threadIdx.x) * 2;
    if (e0 >= N_EDGES) return;
    int u0 = eu[e0], u1 = eu[e0 + 1];
    int i0 = ei[e0], i1 = ei[e0 + 1];
    int w0 = __float_as_int(w[e0]);
    int w1 = __float_as_int(w[e0 + 1]);
    int su0 = rp[u0] + ru[e0];
    int si0 = rp[N_USERS + i0] + ri[e0];
    int su1 = rp[u1] + ru[e0 + 1];
    int si1 = rp[N_USERS + i1] + ri[e0 + 1];
    entries[su0] = make_int2(N_USERS + i0, w0);   // user bucket -> item row
    entries[si0] = make_int2(u0, w0);             // item bucket -> user row
    entries[su1] = make_int2(N_USERS + i1, w1);
    entries[si1] = make_int2(u1, w1);
}

// ---------------- input convert: f32 -> bf16 unified F0 ----------------
__global__ void convert_kernel(const float4* __restrict__ uf,
                               const float4* __restrict__ itf,
                               unsigned short* __restrict__ F0)
{
    const int NU4 = N_USERS * DIM / 4;   // 3,200,000
    const int NT4 = NTOT * DIM / 4;      // 4,800,000
    int idx = blockIdx.x * blockDim.x + threadIdx.x;
    if (idx >= NT4) return;
    float4 v = (idx < NU4) ? uf[idx] : itf[idx - NU4];
    *reinterpret_cast<uint2*>(F0 + (size_t)idx * 4) = pack4(v);
}

// ---------------- unified aggregation (one full layer) ----------------
// 4 rows per wave: quad = lane>>4 handles row wave*4+quad, 16 lanes x 4 dims.
__global__ void agg_kernel(const int* __restrict__ rp,
                           const int2* __restrict__ entries,
                           const unsigned short* __restrict__ src,
                           unsigned short* __restrict__ dst)
{
    int gid = blockIdx.x * blockDim.x + threadIdx.x;
    int lane = gid & 63;
    int quad = lane >> 4;
    int l16 = lane & 15;
    int row = (gid >> 6) * 4 + quad;
    if (row >= NTOT) return;
    int beg = rp[row];
    int end = rp[row + 1];
    int cnt = end - beg;
    int qb = quad << 4;

    float4 a0 = {0,0,0,0}, a1 = {0,0,0,0}, a2 = {0,0,0,0}, a3 = {0,0,0,0};
    for (int base = 0; base < cnt; base += 16) {
        int rem = min(16, cnt - base);
        int2 e = make_int2(0, 0);
        if (l16 < rem) e = entries[beg + base + l16];
        int j = 0;
        for (; j + 3 < rem; j += 4) {
            int c0 = __shfl(e.x, qb + j);     float w0 = __int_as_float(__shfl(e.y, qb + j));
            int c1 = __shfl(e.x, qb + j + 1); float w1 = __int_as_float(__shfl(e.y, qb + j + 1));
            int c2 = __shfl(e.x, qb + j + 2); float w2 = __int_as_float(__shfl(e.y, qb + j + 2));
            int c3 = __shfl(e.x, qb + j + 3); float w3 = __int_as_float(__shfl(e.y, qb + j + 3));
            uint2 v0 = *reinterpret_cast<const uint2*>(src + (size_t)c0 * DIM + l16 * 4);
            uint2 v1 = *reinterpret_cast<const uint2*>(src + (size_t)c1 * DIM + l16 * 4);
            uint2 v2 = *reinterpret_cast<const uint2*>(src + (size_t)c2 * DIM + l16 * 4);
            uint2 v3 = *reinterpret_cast<const uint2*>(src + (size_t)c3 * DIM + l16 * 4);
            fma4(a0, v0, w0); fma4(a1, v1, w1); fma4(a2, v2, w2); fma4(a3, v3, w3);
        }
        for (; j < rem; ++j) {
            int c0 = __shfl(e.x, qb + j);
            float w0 = __int_as_float(__shfl(e.y, qb + j));
            uint2 v0 = *reinterpret_cast<const uint2*>(src + (size_t)c0 * DIM + l16 * 4);
            fma4(a0, v0, w0);
        }
    }
    float4 s;
    s.x = (a0.x + a1.x) + (a2.x + a3.x);
    s.y = (a0.y + a1.y) + (a2.y + a3.y);
    s.z = (a0.z + a1.z) + (a2.z + a3.z);
    s.w = (a0.w + a1.w) + (a2.w + a3.w);
    *reinterpret_cast<uint2*>(dst + (size_t)row * DIM + l16 * 4) = pack4(s);
}

// ---------------- final layer at output rows only ----------------
// out[orow] += 0.25 * segsum over bucket's entries of H2 (bf16).
__global__ void agg_out_kernel(const int* __restrict__ rp,
                               const int2* __restrict__ entries,
                               const unsigned short* __restrict__ src,
                               const int* __restrict__ users,
                               const int* __restrict__ pos,
                               const int* __restrict__ neg,
                               float* __restrict__ out)
{
    int gid = blockIdx.x * blockDim.x + threadIdx.x;
    int lane = gid & 63;
    int quad = lane >> 4;
    int l16 = lane & 15;
    int orow = (gid >> 6) * 4 + quad;
    if (orow >= 3 * BATCH) return;
    int seg = orow >> 13;
    int b = orow & (BATCH - 1);
    int bucket;
    if (seg == 0)      bucket = users[b];
    else if (seg == 1) bucket = N_USERS + pos[b];
    else               bucket = N_USERS + neg[b];

    int beg = rp[bucket];
    int end = rp[bucket + 1];
    int cnt = end - beg;
    int qb = quad << 4;

    float4 a0 = {0,0,0,0}, a1 = {0,0,0,0}, a2 = {0,0,0,0}, a3 = {0,0,0,0};
    for (int base = 0; base < cnt; base += 16) {
        int rem = min(16, cnt - base);
        int2 e = make_int2(0, 0);
        if (l16 < rem) e = entries[beg + base + l16];
        int j = 0;
        for (; j + 3 < rem; j += 4) {
            int c0 = __shfl(e.x, qb + j);     float w0 = __int_as_float(__shfl(e.y, qb + j));
            int c1 = __shfl(e.x, qb + j + 1); float w1 = __int_as_float(__shfl(e.y, qb + j + 1));
            int c2 = __shfl(e.x, qb + j + 2); float w2 = __int_as_float(__shfl(e.y, qb + j + 2));
            int c3 = __shfl(e.x, qb + j + 3); float w3 = __int_as_float(__shfl(e.y, qb + j + 3));
            uint2 v0 = *reinterpret_cast<const uint2*>(src + (size_t)c0 * DIM + l16 * 4);
            uint2 v1 = *reinterpret_cast<const uint2*>(src + (size_t)c1 * DIM + l16 * 4);
            uint2 v2 = *reinterpret_cast<const uint2*>(src + (size_t)c2 * DIM + l16 * 4);
            uint2 v3 = *reinterpret_cast<const uint2*>(src + (size_t)c3 * DIM + l16 * 4);
            fma4(a0, v0, w0); fma4(a1, v1, w1); fma4(a2, v2, w2); fma4(a3, v3, w3);
        }
        for (; j < rem; ++j) {
            int c0 = __shfl(e.x, qb + j);
            float w0 = __int_as_float(__shfl(e.y, qb + j));
            uint2 v0 = *reinterpret_cast<const uint2*>(src + (size_t)c0 * DIM + l16 * 4);
            fma4(a0, v0, w0);
        }
    }
    float4 s;
    s.x = (a0.x + a1.x) + (a2.x + a3.x);
    s.y = (a0.y + a1.y) + (a2.y + a3.y);
    s.z = (a0.z + a1.z) + (a2.z + a3.z);
    s.w = (a0.w + a1.w) + (a2.w + a3.w);
    float* op = out + (size_t)orow * DIM + l16 * 4;
    float4 o = *reinterpret_cast<const float4*>(op);
    o.x += 0.25f * s.x; o.y += 0.25f * s.y;
    o.z += 0.25f * s.z; o.w += 0.25f * s.w;
    *reinterpret_cast<float4*>(op) = o;
}

// ---------------- output h0 init (f32 inputs, no quantization) ----------------
__global__ void out_h0_kernel(const float* __restrict__ u_src,
                              const float* __restrict__ i_src,
                              const int* __restrict__ users,
                              const int* __restrict__ pos,
                              const int* __restrict__ neg,
                              float* __restrict__ out)
{
    int idx = blockIdx.x * blockDim.x + threadIdx.x;
    int row = idx >> 4;
    if (row >= 3 * BATCH) return;
    int d4 = (idx & 15) << 2;
    int seg = row >> 13;
    int b = row & (BATCH - 1);
    const float* src;
    if (seg == 0)      src = u_src + (size_t)users[b] * DIM;
    else if (seg == 1) src = i_src + (size_t)pos[b]   * DIM;
    else               src = i_src + (size_t)neg[b]   * DIM;
    float4 v = *reinterpret_cast<const float4*>(src + d4);
    v.x *= 0.25f; v.y *= 0.25f; v.z *= 0.25f; v.w *= 0.25f;
    *reinterpret_cast<float4*>(out + (size_t)row * DIM + d4) = v;
}

// ---------------- output += 0.25 * H (bf16 unified) ----------------
__global__ void out_add_kernel(const unsigned short* __restrict__ H,
                               const int* __restrict__ users,
                               const int* __restrict__ pos,
                               const int* __restrict__ neg,
                               float* __restrict__ out)
{
    int idx = blockIdx.x * blockDim.x + threadIdx.x;
    int row = idx >> 4;
    if (row >= 3 * BATCH) return;
    int d4 = (idx & 15) << 2;
    int seg = row >> 13;
    int b = row & (BATCH - 1);
    int bucket;
    if (seg == 0)      bucket = users[b];
    else if (seg == 1) bucket = N_USERS + pos[b];
    else               bucket = N_USERS + neg[b];
    uint2 v = *reinterpret_cast<const uint2*>(H + (size_t)bucket * DIM + d4);
    float* op = out + (size_t)row * DIM + d4;
    float4 o = *reinterpret_cast<const float4*>(op);
    o.x += 0.25f * __uint_as_float(v.x << 16);
    o.y += 0.25f * __uint_as_float(v.x & 0xffff0000u);
    o.z += 0.25f * __uint_as_float(v.y << 16);
    o.w += 0.25f * __uint_as_float(v.y & 0xffff0000u);
    *reinterpret_cast<float4*>(op) = o;
}

extern "C" void kernel_launch(void* const* d_in, const int* in_sizes, int n_in,
                              void* d_out, int out_size, void* d_ws, size_t ws_size,
                              hipStream_t stream)
{
    const float* user_feat = (const float*)d_in[0];
    const float* item_feat = (const float*)d_in[1];
    const int*   eu        = (const int*)d_in[2];
    const int*   ei        = (const int*)d_in[3];
    const float* norm      = (const float*)d_in[4];
    const int*   users     = (const int*)d_in[5];
    const int*   pos       = (const int*)d_in[6];
    const int*   neg       = (const int*)d_in[7];
    float* out = (float*)d_out;

    auto align256 = [](size_t x) { return (x + 255) & ~(size_t)255; };
    const size_t hBytes = (size_t)NTOT * DIM * sizeof(unsigned short);  // 38.4 MB

    char* p = (char*)d_ws;
    unsigned short* F0 = (unsigned short*)p; p += align256(hBytes);
    unsigned short* H1 = (unsigned short*)p; p += align256(hBytes);
    unsigned short* H2 = (unsigned short*)p; p += align256(hBytes);
    int*  cnt      = (int*)p;  p += align256((size_t)NTOT * 4);
    int*  rp       = (int*)p;  p += align256((size_t)(NTOT + 1) * 4);
    int*  partials = (int*)p;  p += align256(512 * 4);
    int*  ru       = (int*)p;  p += align256((size_t)N_EDGES * 4);
    int*  ri       = (int*)p;  p += align256((size_t)N_EDGES * 4);
    int2* entries  = (int2*)p; p += align256((size_t)2 * N_EDGES * 8);
    // total ~142 MB

    // ---- CSR build ----
    hipMemsetAsync(cnt, 0, (size_t)NTOT * 4, stream);
    const int edgeBlocks2 = (N_EDGES / 2 + 255) / 256;
    hist_rank_kernel<<<edgeBlocks2, 256, 0, stream>>>(eu, ei, cnt, ru, ri);
    scan_block_sums<<<NBLK, 256, 0, stream>>>(cnt, partials, NTOT);
    scan_partials_k<<<1, 512, 0, stream>>>(partials, rp, NBLK, NTOT);
    scan_final<<<NBLK, 256, 0, stream>>>(cnt, partials, rp, NTOT);
    fill_kernel<<<edgeBlocks2, 256, 0, stream>>>(eu, ei, norm, rp, ru, ri, entries);

    // ---- convert inputs to bf16 unified F0 ----
    const int convBlocks = (NTOT * DIM / 4 + 255) / 256;   // 18750
    convert_kernel<<<convBlocks, 256, 0, stream>>>(
        (const float4*)user_feat, (const float4*)item_feat, F0);

    const int aggBlocks    = NTOT / 16;                    // 18750 (4 rows/wave)
    const int outBlocks    = (3 * BATCH * 16 + 255) / 256; // 1536
    const int aggOutBlocks = (3 * BATCH) / 16;             // 1536

    // out = 0.25 * h0 (f32 inputs)
    out_h0_kernel<<<outBlocks, 256, 0, stream>>>(
        user_feat, item_feat, users, pos, neg, out);

    // layer 1
    agg_kernel<<<aggBlocks, 256, 0, stream>>>(rp, entries, F0, H1);
    out_add_kernel<<<outBlocks, 256, 0, stream>>>(H1, users, pos, neg, out);
    // layer 2
    agg_kernel<<<aggBlocks, 256, 0, stream>>>(rp, entries, H1, H2);
    out_add_kernel<<<outBlocks, 256, 0, stream>>>(H2, users, pos, neg, out);
    // layer 3: only at output rows
    agg_out_kernel<<<aggOutBlocks, 256, 0, stream>>>(
        rp, entries, H2, users, pos, neg, out);
}

// Round 7
// 381.118 us; speedup vs baseline: 13.9343x; 1.0126x over previous
//
#include <hip/hip_runtime.h>

// LightGCN propagation, CSR-gather, bf16 intermediates, unified row space,
// fused launches + layer-2 row pruning.
//
// Rows 0..199999 = users, 200000..299999 = items. Entries store GLOBAL
// opposite-side row ids. Layers:
//   H1 = A*F0 (all rows)   H2 = A*H1 (ONLY rows needed by outputs)
//   layer 3 computed only at the 3*8192 output rows; the final kernel does
//   out += 0.25*(H3 + H2[bucket]) in ONE read-modify-write per element
//   (RACE FIX vs R6: never two block-groups RMW-ing the same out rows).
//
// Launch plan (9 launches):
//   memset(cnt|flags|count) ; fused_pre(hist + f32->bf16 convert + out_h0)
//   scan x3 ; fill ; agg1+flag_scatter ; compact ; agg2(list)+out_add(H1)
//   aggout(+H2 add fused into same thread)

#define N_USERS 200000
#define N_ITEMS 100000
#define N_EDGES 1000000
#define DIM 64
#define BATCH 8192
#define NTOT (N_USERS + N_ITEMS)          // 300000 rows
#define NOUT (3 * BATCH)                  // 24576 output rows
#define SCAN_CHUNK 1024
#define NBLK ((NTOT + SCAN_CHUNK - 1) / SCAN_CHUNK)   // 293

#define HB 3907    // hist blocks: 1 edge/thread
#define CB 9375    // convert blocks: 8 floats/thread (NTOT*DIM/8/256)
#define OB 1536    // output-row blocks: 16 threads/row (NOUT*16/256)
#define AB (NTOT / 16)            // 18750 agg blocks (4 rows/wave)
#define FB ((NOUT + 255) / 256)   // 96 flag-scatter blocks

// ---------- bf16 helpers ----------
__device__ __forceinline__ unsigned f2bf(float f) {   // round-to-nearest-even
    unsigned u = __float_as_uint(f);
    return (u + 0x7fffu + ((u >> 16) & 1u)) >> 16;
}
__device__ __forceinline__ uint2 pack4(float4 v) {
    uint2 o;
    o.x = f2bf(v.x) | (f2bf(v.y) << 16);
    o.y = f2bf(v.z) | (f2bf(v.w) << 16);
    return o;
}
__device__ __forceinline__ void fma4(float4& a, uint2 v, float w) {
    a.x += __uint_as_float(v.x << 16) * w;
    a.y += __uint_as_float(v.x & 0xffff0000u) * w;
    a.z += __uint_as_float(v.y << 16) * w;
    a.w += __uint_as_float(v.y & 0xffff0000u) * w;
}
__device__ __forceinline__ int out_bucket(int orow, const int* users,
                                          const int* pos, const int* neg) {
    int seg = orow >> 13;
    int b = orow & (BATCH - 1);
    if (seg == 0) return users[b];
    if (seg == 1) return N_USERS + pos[b];
    return N_USERS + neg[b];
}

// ---------------- fused pre: hist_rank + convert + out_h0 ----------------
__global__ void fused_pre_kernel(const int* __restrict__ eu,
                                 const int* __restrict__ ei,
                                 int* __restrict__ cnt,
                                 int2* __restrict__ rk,
                                 const float4* __restrict__ uf4,
                                 const float4* __restrict__ if4,
                                 unsigned short* __restrict__ F0,
                                 const float* __restrict__ u_feat,
                                 const float* __restrict__ i_feat,
                                 const int* __restrict__ users,
                                 const int* __restrict__ pos,
                                 const int* __restrict__ neg,
                                 float* __restrict__ out)
{
    int bid = blockIdx.x;
    if (bid < HB) {
        // hist + rank: 1 edge/thread, 2 returning atomics, packed rank store
        int e = bid * 256 + threadIdx.x;
        if (e >= N_EDGES) return;
        int u = eu[e], it = ei[e];
        int r0 = atomicAdd(&cnt[u], 1);
        int r1 = atomicAdd(&cnt[N_USERS + it], 1);
        rk[e] = make_int2(r0, r1);
    } else if (bid < HB + CB) {
        // f32 -> bf16 convert, 8 floats/thread; user/item boundary (12.8M)
        // is a multiple of 8, so a thread never straddles it.
        int j = (bid - HB) * 256 + threadIdx.x;      // [0, 2.4M)
        int f4 = j * 2;                              // float4 index
        const int NU4 = N_USERS * DIM / 4;           // 3.2M
        float4 a, b;
        if (f4 < NU4) { a = uf4[f4]; b = uf4[f4 + 1]; }
        else          { a = if4[f4 - NU4]; b = if4[f4 - NU4 + 1]; }
        uint2 pa = pack4(a), pb = pack4(b);
        *reinterpret_cast<uint4*>(F0 + (size_t)j * 8) =
            make_uint4(pa.x, pa.y, pb.x, pb.y);
    } else {
        // out = 0.25 * h0 at gathered rows (f32 inputs, no quantization)
        int idx = (bid - HB - CB) * 256 + threadIdx.x;
        int row = idx >> 4;
        if (row >= NOUT) return;
        int d4 = (idx & 15) << 2;
        int seg = row >> 13;
        int b = row & (BATCH - 1);
        const float* src;
        if (seg == 0)      src = u_feat + (size_t)users[b] * DIM;
        else if (seg == 1) src = i_feat + (size_t)pos[b]   * DIM;
        else               src = i_feat + (size_t)neg[b]   * DIM;
        float4 v = *reinterpret_cast<const float4*>(src + d4);
        v.x *= 0.25f; v.y *= 0.25f; v.z *= 0.25f; v.w *= 0.25f;
        *reinterpret_cast<float4*>(out + (size_t)row * DIM + d4) = v;
    }
}

// ---------------- scan ----------------
__global__ void scan_block_sums(const int* __restrict__ cnt,
                                int* __restrict__ partials, int n)
{
    __shared__ int s[256];
    int t = threadIdx.x;
    int idx = blockIdx.x * SCAN_CHUNK + t * 4;
    int4 v = make_int4(0, 0, 0, 0);
    if (idx < n) v = *reinterpret_cast<const int4*>(cnt + idx);
    s[t] = v.x + v.y + v.z + v.w;
    __syncthreads();
    for (int off = 128; off > 0; off >>= 1) {
        if (t < off) s[t] += s[t + off];
        __syncthreads();
    }
    if (t == 0) partials[blockIdx.x] = s[0];
}

__global__ void scan_partials_k(int* __restrict__ partials,
                                int* __restrict__ rp, int nb, int n)
{
    __shared__ int s[512];
    int t = threadIdx.x;
    s[t] = (t < nb) ? partials[t] : 0;
    __syncthreads();
    for (int off = 1; off < 512; off <<= 1) {
        int x = (t >= off) ? s[t - off] : 0;
        __syncthreads();
        s[t] += x;
        __syncthreads();
    }
    if (t < nb) partials[t] = (t == 0) ? 0 : s[t - 1];
    if (t == 0) rp[n] = 2 * N_EDGES;
}

__global__ void scan_final(const int* __restrict__ cnt,
                           const int* __restrict__ partials,
                           int* __restrict__ rp, int n)
{
    __shared__ int s[256];
    int t = threadIdx.x;
    int idx = blockIdx.x * SCAN_CHUNK + t * 4;
    int4 v = make_int4(0, 0, 0, 0);
    if (idx < n) v = *reinterpret_cast<const int4*>(cnt + idx);
    int tsum = v.x + v.y + v.z + v.w;
    s[t] = tsum;
    __syncthreads();
    for (int off = 1; off < 256; off <<= 1) {
        int x = (t >= off) ? s[t - off] : 0;
        __syncthreads();
        s[t] += x;
        __syncthreads();
    }
    int base = partials[blockIdx.x] + ((t == 0) ? 0 : s[t - 1]);
    if (idx < n) {
        rp[idx + 0] = base;
        rp[idx + 1] = base + v.x;
        rp[idx + 2] = base + v.x + v.y;
        rp[idx + 3] = base + v.x + v.y + v.z;
    }
}

// ---------------- atomic-free fill ----------------
__global__ void fill_kernel(const int* __restrict__ eu,
                            const int* __restrict__ ei,
                            const float* __restrict__ w,
                            const int* __restrict__ rp,
                            const int2* __restrict__ rk,
                            int2* __restrict__ entries)
{
    int e0 = (blockIdx.x * blockDim.x + threadIdx.x) * 2;
    if (e0 >= N_EDGES) return;
    int u0 = eu[e0], u1 = eu[e0 + 1];
    int i0 = ei[e0], i1 = ei[e0 + 1];
    int w0 = __float_as_int(w[e0]);
    int w1 = __float_as_int(w[e0 + 1]);
    int2 r0 = rk[e0], r1 = rk[e0 + 1];
    int su0 = rp[u0] + r0.x;
    int si0 = rp[N_USERS + i0] + r0.y;
    int su1 = rp[u1] + r1.x;
    int si1 = rp[N_USERS + i1] + r1.y;
    entries[su0] = make_int2(N_USERS + i0, w0);
    entries[si0] = make_int2(u0, w0);
    entries[su1] = make_int2(N_USERS + i1, w1);
    entries[si1] = make_int2(u1, w1);
}

// ---------------- agg core (4 rows/wave) ----------------
__device__ __forceinline__ void agg_row(int row, int l16, int quad,
                                        const int* __restrict__ rp,
                                        const int2* __restrict__ entries,
                                        const unsigned short* __restrict__ src,
                                        float4& s)
{
    int beg = rp[row];
    int end = rp[row + 1];
    int cnt = end - beg;
    int qb = quad << 4;
    float4 a0 = {0,0,0,0}, a1 = {0,0,0,0}, a2 = {0,0,0,0}, a3 = {0,0,0,0};
    for (int base = 0; base < cnt; base += 16) {
        int rem = min(16, cnt - base);
        int2 e = make_int2(0, 0);
        if (l16 < rem) e = entries[beg + base + l16];
        int j = 0;
        for (; j + 3 < rem; j += 4) {
            int c0 = __shfl(e.x, qb + j);     float w0 = __int_as_float(__shfl(e.y, qb + j));
            int c1 = __shfl(e.x, qb + j + 1); float w1 = __int_as_float(__shfl(e.y, qb + j + 1));
            int c2 = __shfl(e.x, qb + j + 2); float w2 = __int_as_float(__shfl(e.y, qb + j + 2));
            int c3 = __shfl(e.x, qb + j + 3); float w3 = __int_as_float(__shfl(e.y, qb + j + 3));
            uint2 v0 = *reinterpret_cast<const uint2*>(src + (size_t)c0 * DIM + l16 * 4);
            uint2 v1 = *reinterpret_cast<const uint2*>(src + (size_t)c1 * DIM + l16 * 4);
            uint2 v2 = *reinterpret_cast<const uint2*>(src + (size_t)c2 * DIM + l16 * 4);
            uint2 v3 = *reinterpret_cast<const uint2*>(src + (size_t)c3 * DIM + l16 * 4);
            fma4(a0, v0, w0); fma4(a1, v1, w1); fma4(a2, v2, w2); fma4(a3, v3, w3);
        }
        for (; j < rem; ++j) {
            int c0 = __shfl(e.x, qb + j);
            float w0 = __int_as_float(__shfl(e.y, qb + j));
            uint2 v0 = *reinterpret_cast<const uint2*>(src + (size_t)c0 * DIM + l16 * 4);
            fma4(a0, v0, w0);
        }
    }
    s.x = (a0.x + a1.x) + (a2.x + a3.x);
    s.y = (a0.y + a1.y) + (a2.y + a3.y);
    s.z = (a0.z + a1.z) + (a2.z + a3.z);
    s.w = (a0.w + a1.w) + (a2.w + a3.w);
}

// ---------------- layer 1 (all rows) + flag scatter ----------------
__global__ void agg1_flag_kernel(const int* __restrict__ rp,
                                 const int2* __restrict__ entries,
                                 const unsigned short* __restrict__ F0,
                                 unsigned short* __restrict__ H1,
                                 const int* __restrict__ users,
                                 const int* __restrict__ pos,
                                 const int* __restrict__ neg,
                                 int* __restrict__ flags)
{
    int bid = blockIdx.x;
    if (bid < AB) {
        int gid = bid * 256 + threadIdx.x;
        int lane = gid & 63;
        int quad = lane >> 4;
        int l16 = lane & 15;
        int row = (gid >> 6) * 4 + quad;
        if (row >= NTOT) return;
        float4 s;
        agg_row(row, l16, quad, rp, entries, F0, s);
        *reinterpret_cast<uint2*>(H1 + (size_t)row * DIM + l16 * 4) = pack4(s);
    } else {
        // flag needed H2 rows: output buckets + cols in their entry lists
        int t = (bid - AB) * 256 + threadIdx.x;
        if (t >= NOUT) return;
        int bucket = out_bucket(t, users, pos, neg);
        flags[bucket] = 1;
        int beg = rp[bucket], end = rp[bucket + 1];
        for (int k = beg; k < end; ++k)
            flags[entries[k].x] = 1;
    }
}

// ---------------- compact flags -> row list ----------------
__global__ void compact_kernel(const int* __restrict__ flags,
                               int* __restrict__ list,
                               int* __restrict__ count)
{
    int t = blockIdx.x * blockDim.x + threadIdx.x;
    int idx = t * 4;
    if (idx >= NTOT) return;
    int4 f = *reinterpret_cast<const int4*>(flags + idx);
    int loc[4]; int k = 0;
    if (f.x) loc[k++] = idx;
    if (f.y) loc[k++] = idx + 1;
    if (f.z) loc[k++] = idx + 2;
    if (f.w) loc[k++] = idx + 3;
    if (k) {
        int base = atomicAdd(count, k);
        for (int m = 0; m < k; ++m) list[base + m] = loc[m];
    }
}

// ---------------- layer 2 (listed rows only) + out += 0.25*H1 ----------------
// Safe fusion: branch A writes H2, branch B RMWs out — disjoint arrays.
__global__ void agg2_add1_kernel(const int* __restrict__ rp,
                                 const int2* __restrict__ entries,
                                 const unsigned short* __restrict__ H1,
                                 unsigned short* __restrict__ H2,
                                 const int* __restrict__ list,
                                 const int* __restrict__ count,
                                 const int* __restrict__ users,
                                 const int* __restrict__ pos,
                                 const int* __restrict__ neg,
                                 float* __restrict__ out)
{
    int bid = blockIdx.x;
    if (bid < AB) {
        int gid = bid * 256 + threadIdx.x;
        int lane = gid & 63;
        int quad = lane >> 4;
        int l16 = lane & 15;
        int idx4 = (gid >> 6) * 4 + quad;
        int n = *count;
        if (idx4 >= n) return;
        int row = list[idx4];
        float4 s;
        agg_row(row, l16, quad, rp, entries, H1, s);
        *reinterpret_cast<uint2*>(H2 + (size_t)row * DIM + l16 * 4) = pack4(s);
    } else {
        int idx = (bid - AB) * 256 + threadIdx.x;
        int row = idx >> 4;
        if (row >= NOUT) return;
        int d4 = (idx & 15) << 2;
        int bucket = out_bucket(row, users, pos, neg);
        uint2 v = *reinterpret_cast<const uint2*>(H1 + (size_t)bucket * DIM + d4);
        float* op = out + (size_t)row * DIM + d4;
        float4 o = *reinterpret_cast<const float4*>(op);
        o.x += 0.25f * __uint_as_float(v.x << 16);
        o.y += 0.25f * __uint_as_float(v.x & 0xffff0000u);
        o.z += 0.25f * __uint_as_float(v.y << 16);
        o.w += 0.25f * __uint_as_float(v.y & 0xffff0000u);
        *reinterpret_cast<float4*>(op) = o;
    }
}

// ---------------- layer 3 at output rows, H2 add fused IN-THREAD ----------------
// out[orow] += 0.25 * (segsum(H2 gather) + H2[bucket]) — single RMW per elem,
// no cross-block aliasing on out.
__global__ void aggout_add2_kernel(const int* __restrict__ rp,
                                   const int2* __restrict__ entries,
                                   const unsigned short* __restrict__ H2,
                                   const int* __restrict__ users,
                                   const int* __restrict__ pos,
                                   const int* __restrict__ neg,
                                   float* __restrict__ out)
{
    int gid = blockIdx.x * 256 + threadIdx.x;
    int lane = gid & 63;
    int quad = lane >> 4;
    int l16 = lane & 15;
    int orow = (gid >> 6) * 4 + quad;
    if (orow >= NOUT) return;
    int bucket = out_bucket(orow, users, pos, neg);
    float4 s;
    agg_row(bucket, l16, quad, rp, entries, H2, s);
    uint2 v = *reinterpret_cast<const uint2*>(H2 + (size_t)bucket * DIM + l16 * 4);
    s.x += __uint_as_float(v.x << 16);
    s.y += __uint_as_float(v.x & 0xffff0000u);
    s.z += __uint_as_float(v.y << 16);
    s.w += __uint_as_float(v.y & 0xffff0000u);
    float* op = out + (size_t)orow * DIM + l16 * 4;
    float4 o = *reinterpret_cast<const float4*>(op);
    o.x += 0.25f * s.x; o.y += 0.25f * s.y;
    o.z += 0.25f * s.z; o.w += 0.25f * s.w;
    *reinterpret_cast<float4*>(op) = o;
}

extern "C" void kernel_launch(void* const* d_in, const int* in_sizes, int n_in,
                              void* d_out, int out_size, void* d_ws, size_t ws_size,
                              hipStream_t stream)
{
    const float* user_feat = (const float*)d_in[0];
    const float* item_feat = (const float*)d_in[1];
    const int*   eu        = (const int*)d_in[2];
    const int*   ei        = (const int*)d_in[3];
    const float* norm      = (const float*)d_in[4];
    const int*   users     = (const int*)d_in[5];
    const int*   pos       = (const int*)d_in[6];
    const int*   neg       = (const int*)d_in[7];
    float* out = (float*)d_out;

    auto align256 = [](size_t x) { return (x + 255) & ~(size_t)255; };
    const size_t hBytes = (size_t)NTOT * DIM * sizeof(unsigned short);  // 38.4 MB

    char* p = (char*)d_ws;
    unsigned short* F0 = (unsigned short*)p; p += align256(hBytes);
    unsigned short* H1 = (unsigned short*)p; p += align256(hBytes);
    unsigned short* H2 = (unsigned short*)p; p += align256(hBytes);
    // cnt | flags | count live in one contiguous memset region
    int* cnt   = (int*)p;  p += align256((size_t)(2 * NTOT + 16) * 4);
    int* flags = cnt + NTOT;
    int* count = cnt + 2 * NTOT;
    int*  rp       = (int*)p;  p += align256((size_t)(NTOT + 1) * 4);
    int*  partials = (int*)p;  p += align256(512 * 4);
    int2* rk       = (int2*)p; p += align256((size_t)N_EDGES * 8);
    int*  list     = (int*)p;  p += align256((size_t)NTOT * 4);
    int2* entries  = (int2*)p; p += align256((size_t)2 * N_EDGES * 8);
    // total ~145 MB

    hipMemsetAsync(cnt, 0, (size_t)(2 * NTOT + 16) * 4, stream);

    // hist + convert + out_h0 fused
    fused_pre_kernel<<<HB + CB + OB, 256, 0, stream>>>(
        eu, ei, cnt, rk,
        (const float4*)user_feat, (const float4*)item_feat, F0,
        user_feat, item_feat, users, pos, neg, out);

    scan_block_sums<<<NBLK, 256, 0, stream>>>(cnt, partials, NTOT);
    scan_partials_k<<<1, 512, 0, stream>>>(partials, rp, NBLK, NTOT);
    scan_final<<<NBLK, 256, 0, stream>>>(cnt, partials, rp, NTOT);

    const int edgeBlocks2 = (N_EDGES / 2 + 255) / 256;
    fill_kernel<<<edgeBlocks2, 256, 0, stream>>>(eu, ei, norm, rp, rk, entries);

    // layer 1 (all rows) + flag scatter for needed-H2 set
    agg1_flag_kernel<<<AB + FB, 256, 0, stream>>>(
        rp, entries, F0, H1, users, pos, neg, flags);

    compact_kernel<<<(NTOT / 4 + 255) / 256, 256, 0, stream>>>(flags, list, count);

    // layer 2 (listed rows) + out += 0.25*H1
    agg2_add1_kernel<<<AB + OB, 256, 0, stream>>>(
        rp, entries, H1, H2, list, count, users, pos, neg, out);

    // layer 3 at output rows with in-thread H2 add
    aggout_add2_kernel<<<NOUT / 16, 256, 0, stream>>>(
        rp, entries, H2, users, pos, neg, out);
}

// Round 8
// 373.163 us; speedup vs baseline: 14.2313x; 1.0213x over previous
//
#include <hip/hip_runtime.h>

// LightGCN propagation, CSR-gather, bf16 intermediates, unified row space,
// fused launches, layer-2 row pruning, deep-MLP hist/fill/agg.
//
// Rows 0..199999 = users, 200000..299999 = items. Entries store GLOBAL
// opposite-side row ids. H1 = A*F0 (all rows); H2 = A*H1 (only rows needed
// by outputs, via flag+compact); layer 3 only at the 3*8192 output rows with
// the H2 contribution added in-thread (single RMW on out — no cross-block
// aliasing).
//
// MLP design points (R7 post-mortem: hist was 2-outstanding-atomic bound):
//   hist: 8 edges/thread -> 16 outstanding returning atomics
//   fill: 4 edges/thread -> 8 outstanding rp gathers + 8 independent stores
//   agg:  8-deep unrolled gather loop (8 x 512B wave-gathers in flight)

#define N_USERS 200000
#define N_ITEMS 100000
#define N_EDGES 1000000
#define DIM 64
#define BATCH 8192
#define NTOT (N_USERS + N_ITEMS)          // 300000 rows
#define NOUT (3 * BATCH)                  // 24576 output rows
#define SCAN_CHUNK 1024
#define NBLK ((NTOT + SCAN_CHUNK - 1) / SCAN_CHUNK)   // 293

#define HB ((N_EDGES / 8 + 255) / 256)    // 489  hist blocks (8 edges/thread)
#define CB (NTOT * DIM / 8 / 256)         // 9375 convert blocks
#define OB (NOUT * 16 / 256)              // 1536 output-row blocks
#define AB (NTOT / 16)                    // 18750 agg blocks (4 rows/wave)
#define FB ((NOUT + 255) / 256)           // 96 flag-scatter blocks

// ---------- bf16 helpers ----------
__device__ __forceinline__ unsigned f2bf(float f) {   // round-to-nearest-even
    unsigned u = __float_as_uint(f);
    return (u + 0x7fffu + ((u >> 16) & 1u)) >> 16;
}
__device__ __forceinline__ uint2 pack4(float4 v) {
    uint2 o;
    o.x = f2bf(v.x) | (f2bf(v.y) << 16);
    o.y = f2bf(v.z) | (f2bf(v.w) << 16);
    return o;
}
__device__ __forceinline__ void fma4(float4& a, uint2 v, float w) {
    a.x += __uint_as_float(v.x << 16) * w;
    a.y += __uint_as_float(v.x & 0xffff0000u) * w;
    a.z += __uint_as_float(v.y << 16) * w;
    a.w += __uint_as_float(v.y & 0xffff0000u) * w;
}
__device__ __forceinline__ int out_bucket(int orow, const int* users,
                                          const int* pos, const int* neg) {
    int seg = orow >> 13;
    int b = orow & (BATCH - 1);
    if (seg == 0) return users[b];
    if (seg == 1) return N_USERS + pos[b];
    return N_USERS + neg[b];
}

// ---------------- fused pre: hist_rank + convert + out_h0 ----------------
__global__ void fused_pre_kernel(const int* __restrict__ eu,
                                 const int* __restrict__ ei,
                                 int* __restrict__ cnt,
                                 int2* __restrict__ rk,
                                 const float4* __restrict__ uf4,
                                 const float4* __restrict__ if4,
                                 unsigned short* __restrict__ F0,
                                 const float* __restrict__ u_feat,
                                 const float* __restrict__ i_feat,
                                 const int* __restrict__ users,
                                 const int* __restrict__ pos,
                                 const int* __restrict__ neg,
                                 float* __restrict__ out)
{
    int bid = blockIdx.x;
    if (bid < HB) {
        // hist + rank: 8 edges/thread, 16 outstanding returning atomics
        int e0 = (bid * 256 + threadIdx.x) * 8;
        if (e0 >= N_EDGES) return;
        int4 u0 = *reinterpret_cast<const int4*>(eu + e0);
        int4 u1 = *reinterpret_cast<const int4*>(eu + e0 + 4);
        int4 i0 = *reinterpret_cast<const int4*>(ei + e0);
        int4 i1 = *reinterpret_cast<const int4*>(ei + e0 + 4);
        int a0 = atomicAdd(&cnt[u0.x], 1);
        int a1 = atomicAdd(&cnt[u0.y], 1);
        int a2 = atomicAdd(&cnt[u0.z], 1);
        int a3 = atomicAdd(&cnt[u0.w], 1);
        int a4 = atomicAdd(&cnt[u1.x], 1);
        int a5 = atomicAdd(&cnt[u1.y], 1);
        int a6 = atomicAdd(&cnt[u1.z], 1);
        int a7 = atomicAdd(&cnt[u1.w], 1);
        int b0 = atomicAdd(&cnt[N_USERS + i0.x], 1);
        int b1 = atomicAdd(&cnt[N_USERS + i0.y], 1);
        int b2 = atomicAdd(&cnt[N_USERS + i0.z], 1);
        int b3 = atomicAdd(&cnt[N_USERS + i0.w], 1);
        int b4 = atomicAdd(&cnt[N_USERS + i1.x], 1);
        int b5 = atomicAdd(&cnt[N_USERS + i1.y], 1);
        int b6 = atomicAdd(&cnt[N_USERS + i1.z], 1);
        int b7 = atomicAdd(&cnt[N_USERS + i1.w], 1);
        int4* rk4 = reinterpret_cast<int4*>(rk + e0);   // 2 edges per int4
        rk4[0] = make_int4(a0, b0, a1, b1);
        rk4[1] = make_int4(a2, b2, a3, b3);
        rk4[2] = make_int4(a4, b4, a5, b5);
        rk4[3] = make_int4(a6, b6, a7, b7);
    } else if (bid < HB + CB) {
        // f32 -> bf16 convert, 8 floats/thread; boundary (12.8M) % 8 == 0.
        int j = (bid - HB) * 256 + threadIdx.x;      // [0, 2.4M)
        int f4 = j * 2;
        const int NU4 = N_USERS * DIM / 4;           // 3.2M
        float4 a, b;
        if (f4 < NU4) { a = uf4[f4]; b = uf4[f4 + 1]; }
        else          { a = if4[f4 - NU4]; b = if4[f4 - NU4 + 1]; }
        uint2 pa = pack4(a), pb = pack4(b);
        *reinterpret_cast<uint4*>(F0 + (size_t)j * 8) =
            make_uint4(pa.x, pa.y, pb.x, pb.y);
    } else {
        // out = 0.25 * h0 at gathered rows (f32 inputs, no quantization)
        int idx = (bid - HB - CB) * 256 + threadIdx.x;
        int row = idx >> 4;
        if (row >= NOUT) return;
        int d4 = (idx & 15) << 2;
        int seg = row >> 13;
        int b = row & (BATCH - 1);
        const float* src;
        if (seg == 0)      src = u_feat + (size_t)users[b] * DIM;
        else if (seg == 1) src = i_feat + (size_t)pos[b]   * DIM;
        else               src = i_feat + (size_t)neg[b]   * DIM;
        float4 v = *reinterpret_cast<const float4*>(src + d4);
        v.x *= 0.25f; v.y *= 0.25f; v.z *= 0.25f; v.w *= 0.25f;
        *reinterpret_cast<float4*>(out + (size_t)row * DIM + d4) = v;
    }
}

// ---------------- scan ----------------
__global__ void scan_block_sums(const int* __restrict__ cnt,
                                int* __restrict__ partials, int n)
{
    __shared__ int s[256];
    int t = threadIdx.x;
    int idx = blockIdx.x * SCAN_CHUNK + t * 4;
    int4 v = make_int4(0, 0, 0, 0);
    if (idx < n) v = *reinterpret_cast<const int4*>(cnt + idx);
    s[t] = v.x + v.y + v.z + v.w;
    __syncthreads();
    for (int off = 128; off > 0; off >>= 1) {
        if (t < off) s[t] += s[t + off];
        __syncthreads();
    }
    if (t == 0) partials[blockIdx.x] = s[0];
}

__global__ void scan_partials_k(int* __restrict__ partials,
                                int* __restrict__ rp, int nb, int n)
{
    __shared__ int s[512];
    int t = threadIdx.x;
    s[t] = (t < nb) ? partials[t] : 0;
    __syncthreads();
    for (int off = 1; off < 512; off <<= 1) {
        int x = (t >= off) ? s[t - off] : 0;
        __syncthreads();
        s[t] += x;
        __syncthreads();
    }
    if (t < nb) partials[t] = (t == 0) ? 0 : s[t - 1];
    if (t == 0) rp[n] = 2 * N_EDGES;
}

__global__ void scan_final(const int* __restrict__ cnt,
                           const int* __restrict__ partials,
                           int* __restrict__ rp, int n)
{
    __shared__ int s[256];
    int t = threadIdx.x;
    int idx = blockIdx.x * SCAN_CHUNK + t * 4;
    int4 v = make_int4(0, 0, 0, 0);
    if (idx < n) v = *reinterpret_cast<const int4*>(cnt + idx);
    int tsum = v.x + v.y + v.z + v.w;
    s[t] = tsum;
    __syncthreads();
    for (int off = 1; off < 256; off <<= 1) {
        int x = (t >= off) ? s[t - off] : 0;
        __syncthreads();
        s[t] += x;
        __syncthreads();
    }
    int base = partials[blockIdx.x] + ((t == 0) ? 0 : s[t - 1]);
    if (idx < n) {
        rp[idx + 0] = base;
        rp[idx + 1] = base + v.x;
        rp[idx + 2] = base + v.x + v.y;
        rp[idx + 3] = base + v.x + v.y + v.z;
    }
}

// ---------------- atomic-free fill: 4 edges/thread ----------------
__global__ void fill_kernel(const int* __restrict__ eu,
                            const int* __restrict__ ei,
                            const float* __restrict__ w,
                            const int* __restrict__ rp,
                            const int2* __restrict__ rk,
                            int2* __restrict__ entries)
{
    int e0 = (blockIdx.x * blockDim.x + threadIdx.x) * 4;
    if (e0 >= N_EDGES) return;
    int4 u  = *reinterpret_cast<const int4*>(eu + e0);
    int4 it = *reinterpret_cast<const int4*>(ei + e0);
    float4 wv = *reinterpret_cast<const float4*>(w + e0);
    int4 r01 = *reinterpret_cast<const int4*>(rk + e0);       // ru0,ri0,ru1,ri1
    int4 r23 = *reinterpret_cast<const int4*>(rk + e0 + 2);   // ru2,ri2,ru3,ri3
    // 8 independent rp gathers
    int pu0 = rp[u.x], pu1 = rp[u.y], pu2 = rp[u.z], pu3 = rp[u.w];
    int pi0 = rp[N_USERS + it.x], pi1 = rp[N_USERS + it.y];
    int pi2 = rp[N_USERS + it.z], pi3 = rp[N_USERS + it.w];
    int w0 = __float_as_int(wv.x), w1 = __float_as_int(wv.y);
    int w2 = __float_as_int(wv.z), w3 = __float_as_int(wv.w);
    // 8 independent scattered stores
    entries[pu0 + r01.x] = make_int2(N_USERS + it.x, w0);
    entries[pi0 + r01.y] = make_int2(u.x, w0);
    entries[pu1 + r01.z] = make_int2(N_USERS + it.y, w1);
    entries[pi1 + r01.w] = make_int2(u.y, w1);
    entries[pu2 + r23.x] = make_int2(N_USERS + it.z, w2);
    entries[pi2 + r23.y] = make_int2(u.z, w2);
    entries[pu3 + r23.z] = make_int2(N_USERS + it.w, w3);
    entries[pi3 + r23.w] = make_int2(u.w, w3);
}

// ---------------- agg core (4 rows/wave, 8-deep unroll) ----------------
#define GATH(idx, acc)                                                        \
    {                                                                         \
        int c = __shfl(e.x, qb + (idx));                                      \
        float ww = __int_as_float(__shfl(e.y, qb + (idx)));                   \
        uint2 v = *reinterpret_cast<const uint2*>(                            \
            src + (size_t)c * DIM + l16 * 4);                                 \
        fma4(acc, v, ww);                                                     \
    }

__device__ __forceinline__ void agg_row(int row, int l16, int quad,
                                        const int* __restrict__ rp,
                                        const int2* __restrict__ entries,
                                        const unsigned short* __restrict__ src,
                                        float4& s)
{
    int beg = rp[row];
    int end = rp[row + 1];
    int cnt = end - beg;
    int qb = quad << 4;
    float4 a0 = {0,0,0,0}, a1 = {0,0,0,0}, a2 = {0,0,0,0}, a3 = {0,0,0,0};
    for (int base = 0; base < cnt; base += 16) {
        int rem = min(16, cnt - base);
        int2 e = make_int2(0, 0);
        if (l16 < rem) e = entries[beg + base + l16];
        int j = 0;
        for (; j + 7 < rem; j += 8) {
            GATH(j + 0, a0) GATH(j + 1, a1) GATH(j + 2, a2) GATH(j + 3, a3)
            GATH(j + 4, a0) GATH(j + 5, a1) GATH(j + 6, a2) GATH(j + 7, a3)
        }
        if (j + 3 < rem) {
            GATH(j + 0, a0) GATH(j + 1, a1) GATH(j + 2, a2) GATH(j + 3, a3)
            j += 4;
        }
        if (j + 1 < rem) {
            GATH(j + 0, a0) GATH(j + 1, a1)
            j += 2;
        }
        if (j < rem) GATH(j, a2)
    }
    s.x = (a0.x + a1.x) + (a2.x + a3.x);
    s.y = (a0.y + a1.y) + (a2.y + a3.y);
    s.z = (a0.z + a1.z) + (a2.z + a3.z);
    s.w = (a0.w + a1.w) + (a2.w + a3.w);
}

// ---------------- layer 1 (all rows) + flag scatter ----------------
__global__ void agg1_flag_kernel(const int* __restrict__ rp,
                                 const int2* __restrict__ entries,
                                 const unsigned short* __restrict__ F0,
                                 unsigned short* __restrict__ H1,
                                 const int* __restrict__ users,
                                 const int* __restrict__ pos,
                                 const int* __restrict__ neg,
                                 int* __restrict__ flags)
{
    int bid = blockIdx.x;
    if (bid < AB) {
        int gid = bid * 256 + threadIdx.x;
        int lane = gid & 63;
        int quad = lane >> 4;
        int l16 = lane & 15;
        int row = (gid >> 6) * 4 + quad;
        if (row >= NTOT) return;
        float4 s;
        agg_row(row, l16, quad, rp, entries, F0, s);
        *reinterpret_cast<uint2*>(H1 + (size_t)row * DIM + l16 * 4) = pack4(s);
    } else {
        // flag needed H2 rows: output buckets + cols in their entry lists
        int t = (bid - AB) * 256 + threadIdx.x;
        if (t >= NOUT) return;
        int bucket = out_bucket(t, users, pos, neg);
        flags[bucket] = 1;
        int beg = rp[bucket], end = rp[bucket + 1];
        for (int k = beg; k < end; ++k)
            flags[entries[k].x] = 1;
    }
}

// ---------------- compact flags -> row list ----------------
__global__ void compact_kernel(const int* __restrict__ flags,
                               int* __restrict__ list,
                               int* __restrict__ count)
{
    int t = blockIdx.x * blockDim.x + threadIdx.x;
    int idx = t * 4;
    if (idx >= NTOT) return;
    int4 f = *reinterpret_cast<const int4*>(flags + idx);
    int loc[4]; int k = 0;
    if (f.x) loc[k++] = idx;
    if (f.y) loc[k++] = idx + 1;
    if (f.z) loc[k++] = idx + 2;
    if (f.w) loc[k++] = idx + 3;
    if (k) {
        int base = atomicAdd(count, k);
        for (int m = 0; m < k; ++m) list[base + m] = loc[m];
    }
}

// ---------------- layer 2 (listed rows only) + out += 0.25*H1 ----------------
// Safe fusion: branch A writes H2, branch B RMWs out — disjoint arrays.
__global__ void agg2_add1_kernel(const int* __restrict__ rp,
                                 const int2* __restrict__ entries,
                                 const unsigned short* __restrict__ H1,
                                 unsigned short* __restrict__ H2,
                                 const int* __restrict__ list,
                                 const int* __restrict__ count,
                                 const int* __restrict__ users,
                                 const int* __restrict__ pos,
                                 const int* __restrict__ neg,
                                 float* __restrict__ out)
{
    int bid = blockIdx.x;
    if (bid < AB) {
        int gid = bid * 256 + threadIdx.x;
        int lane = gid & 63;
        int quad = lane >> 4;
        int l16 = lane & 15;
        int idx4 = (gid >> 6) * 4 + quad;
        int n = *count;
        if (idx4 >= n) return;
        int row = list[idx4];
        float4 s;
        agg_row(row, l16, quad, rp, entries, H1, s);
        *reinterpret_cast<uint2*>(H2 + (size_t)row * DIM + l16 * 4) = pack4(s);
    } else {
        int idx = (bid - AB) * 256 + threadIdx.x;
        int row = idx >> 4;
        if (row >= NOUT) return;
        int d4 = (idx & 15) << 2;
        int bucket = out_bucket(row, users, pos, neg);
        uint2 v = *reinterpret_cast<const uint2*>(H1 + (size_t)bucket * DIM + d4);
        float* op = out + (size_t)row * DIM + d4;
        float4 o = *reinterpret_cast<const float4*>(op);
        o.x += 0.25f * __uint_as_float(v.x << 16);
        o.y += 0.25f * __uint_as_float(v.x & 0xffff0000u);
        o.z += 0.25f * __uint_as_float(v.y << 16);
        o.w += 0.25f * __uint_as_float(v.y & 0xffff0000u);
        *reinterpret_cast<float4*>(op) = o;
    }
}

// ---------------- layer 3 at output rows, H2 add fused IN-THREAD ----------------
__global__ void aggout_add2_kernel(const int* __restrict__ rp,
                                   const int2* __restrict__ entries,
                                   const unsigned short* __restrict__ H2,
                                   const int* __restrict__ users,
                                   const int* __restrict__ pos,
                                   const int* __restrict__ neg,
                                   float* __restrict__ out)
{
    int gid = blockIdx.x * 256 + threadIdx.x;
    int lane = gid & 63;
    int quad = lane >> 4;
    int l16 = lane & 15;
    int orow = (gid >> 6) * 4 + quad;
    if (orow >= NOUT) return;
    int bucket = out_bucket(orow, users, pos, neg);
    float4 s;
    agg_row(bucket, l16, quad, rp, entries, H2, s);
    uint2 v = *reinterpret_cast<const uint2*>(H2 + (size_t)bucket * DIM + l16 * 4);
    s.x += __uint_as_float(v.x << 16);
    s.y += __uint_as_float(v.x & 0xffff0000u);
    s.z += __uint_as_float(v.y << 16);
    s.w += __uint_as_float(v.y & 0xffff0000u);
    float* op = out + (size_t)orow * DIM + l16 * 4;
    float4 o = *reinterpret_cast<const float4*>(op);
    o.x += 0.25f * s.x; o.y += 0.25f * s.y;
    o.z += 0.25f * s.z; o.w += 0.25f * s.w;
    *reinterpret_cast<float4*>(op) = o;
}

extern "C" void kernel_launch(void* const* d_in, const int* in_sizes, int n_in,
                              void* d_out, int out_size, void* d_ws, size_t ws_size,
                              hipStream_t stream)
{
    const float* user_feat = (const float*)d_in[0];
    const float* item_feat = (const float*)d_in[1];
    const int*   eu        = (const int*)d_in[2];
    const int*   ei        = (const int*)d_in[3];
    const float* norm      = (const float*)d_in[4];
    const int*   users     = (const int*)d_in[5];
    const int*   pos       = (const int*)d_in[6];
    const int*   neg       = (const int*)d_in[7];
    float* out = (float*)d_out;

    auto align256 = [](size_t x) { return (x + 255) & ~(size_t)255; };
    const size_t hBytes = (size_t)NTOT * DIM * sizeof(unsigned short);  // 38.4 MB

    char* p = (char*)d_ws;
    unsigned short* F0 = (unsigned short*)p; p += align256(hBytes);
    unsigned short* H1 = (unsigned short*)p; p += align256(hBytes);
    unsigned short* H2 = (unsigned short*)p; p += align256(hBytes);
    // cnt | flags | count live in one contiguous memset region
    int* cnt   = (int*)p;  p += align256((size_t)(2 * NTOT + 16) * 4);
    int* flags = cnt + NTOT;
    int* count = cnt + 2 * NTOT;
    int*  rp       = (int*)p;  p += align256((size_t)(NTOT + 1) * 4);
    int*  partials = (int*)p;  p += align256(512 * 4);
    int2* rk       = (int2*)p; p += align256((size_t)N_EDGES * 8);
    int*  list     = (int*)p;  p += align256((size_t)NTOT * 4);
    int2* entries  = (int2*)p; p += align256((size_t)2 * N_EDGES * 8);
    // total ~145 MB

    hipMemsetAsync(cnt, 0, (size_t)(2 * NTOT + 16) * 4, stream);

    // hist + convert + out_h0 fused
    fused_pre_kernel<<<HB + CB + OB, 256, 0, stream>>>(
        eu, ei, cnt, rk,
        (const float4*)user_feat, (const float4*)item_feat, F0,
        user_feat, item_feat, users, pos, neg, out);

    scan_block_sums<<<NBLK, 256, 0, stream>>>(cnt, partials, NTOT);
    scan_partials_k<<<1, 512, 0, stream>>>(partials, rp, NBLK, NTOT);
    scan_final<<<NBLK, 256, 0, stream>>>(cnt, partials, rp, NTOT);

    const int fillBlocks = (N_EDGES / 4 + 255) / 256;   // 977
    fill_kernel<<<fillBlocks, 256, 0, stream>>>(eu, ei, norm, rp, rk, entries);

    // layer 1 (all rows) + flag scatter for needed-H2 set
    agg1_flag_kernel<<<AB + FB, 256, 0, stream>>>(
        rp, entries, F0, H1, users, pos, neg, flags);

    compact_kernel<<<(NTOT / 4 + 255) / 256, 256, 0, stream>>>(flags, list, count);

    // layer 2 (listed rows) + out += 0.25*H1
    agg2_add1_kernel<<<AB + OB, 256, 0, stream>>>(
        rp, entries, H1, H2, list, count, users, pos, neg, out);

    // layer 3 at output rows with in-thread H2 add
    aggout_add2_kernel<<<NOUT / 16, 256, 0, stream>>>(
        rp, entries, H2, users, pos, neg, out);
}

// Round 9
// 312.010 us; speedup vs baseline: 17.0206x; 1.1960x over previous
//
#include <hip/hip_runtime.h>

// LightGCN propagation, CSR-gather, bf16 intermediates, unified row space.
// R9: ATOMIC-FREE CSR build (two-level partition sort) — R8 showed returning
// device-scope atomics wall at ~22 G/s regardless of per-wave MLP, so the 2M
// returning hist atomics are replaced by:
//   A: per-block LDS hist over 293 partitions (bucket>>10), fire-and-forget
//      global accumulation (+ fused f32->bf16 convert + out_h0).
//   S: 1-block scan of partition totals -> partStart, gcur.
//   B: partition scatter: per-block LDS hist, ONE returning atomic per
//      (block,partition) to reserve space (143K vs 2M), LDS-cursor scatter of
//      packed 8B records into partition-contiguous partBuf.
//   C: one block per partition: LDS 1024-bucket hist + scan -> writes rp
//      slice directly (replaces the 3 global scan kernels) -> LDS-cursor
//      scatter into entries (55KB window => good write locality).
// Aggregation (unchanged from R8): H1 = A*F0 all rows; H2 = A*H1 only at
// rows needed by outputs (flag+compact); layer 3 only at output rows with
// in-thread H2 add (single RMW on out).

#define N_USERS 200000
#define N_ITEMS 100000
#define N_EDGES 1000000
#define DIM 64
#define BATCH 8192
#define NTOT (N_USERS + N_ITEMS)          // 300000 rows
#define NOUT (3 * BATCH)                  // 24576 output rows
#define NPART 293                         // ceil(NTOT / 1024)
#define PLOCAL 1024

#define HA 489                            // hist blocks: 8 edges/thread
#define CB (NTOT * DIM / 8 / 256)         // 9375 convert blocks
#define OB (NOUT * 16 / 256)              // 1536 out_h0 blocks
#define AB (NTOT / 16)                    // 18750 agg blocks (4 rows/wave)
#define FB ((NOUT + 255) / 256)           // 96 flag-scatter blocks

// ---------- bf16 helpers ----------
__device__ __forceinline__ unsigned f2bf(float f) {   // round-to-nearest-even
    unsigned u = __float_as_uint(f);
    return (u + 0x7fffu + ((u >> 16) & 1u)) >> 16;
}
__device__ __forceinline__ uint2 pack4(float4 v) {
    uint2 o;
    o.x = f2bf(v.x) | (f2bf(v.y) << 16);
    o.y = f2bf(v.z) | (f2bf(v.w) << 16);
    return o;
}
__device__ __forceinline__ void fma4(float4& a, uint2 v, float w) {
    a.x += __uint_as_float(v.x << 16) * w;
    a.y += __uint_as_float(v.x & 0xffff0000u) * w;
    a.z += __uint_as_float(v.y << 16) * w;
    a.w += __uint_as_float(v.y & 0xffff0000u) * w;
}
__device__ __forceinline__ int out_bucket(int orow, const int* users,
                                          const int* pos, const int* neg) {
    int seg = orow >> 13;
    int b = orow & (BATCH - 1);
    if (seg == 0) return users[b];
    if (seg == 1) return N_USERS + pos[b];
    return N_USERS + neg[b];
}

// ---------------- A: partition hist + convert + out_h0 ----------------
__global__ void fused_pre_kernel(const int* __restrict__ eu,
                                 const int* __restrict__ ei,
                                 int* __restrict__ partTotals,
                                 const float4* __restrict__ uf4,
                                 const float4* __restrict__ if4,
                                 unsigned short* __restrict__ F0,
                                 const float* __restrict__ u_feat,
                                 const float* __restrict__ i_feat,
                                 const int* __restrict__ users,
                                 const int* __restrict__ pos,
                                 const int* __restrict__ neg,
                                 float* __restrict__ out)
{
    __shared__ int lh[NPART];
    int bid = blockIdx.x;
    if (bid < HA) {
        for (int k = threadIdx.x; k < NPART; k += 256) lh[k] = 0;
        __syncthreads();
        int e0 = (bid * 256 + threadIdx.x) * 8;
        if (e0 < N_EDGES) {
            int4 u0 = *reinterpret_cast<const int4*>(eu + e0);
            int4 u1 = *reinterpret_cast<const int4*>(eu + e0 + 4);
            int4 i0 = *reinterpret_cast<const int4*>(ei + e0);
            int4 i1 = *reinterpret_cast<const int4*>(ei + e0 + 4);
            atomicAdd(&lh[u0.x >> 10], 1);
            atomicAdd(&lh[u0.y >> 10], 1);
            atomicAdd(&lh[u0.z >> 10], 1);
            atomicAdd(&lh[u0.w >> 10], 1);
            atomicAdd(&lh[u1.x >> 10], 1);
            atomicAdd(&lh[u1.y >> 10], 1);
            atomicAdd(&lh[u1.z >> 10], 1);
            atomicAdd(&lh[u1.w >> 10], 1);
            atomicAdd(&lh[(N_USERS + i0.x) >> 10], 1);
            atomicAdd(&lh[(N_USERS + i0.y) >> 10], 1);
            atomicAdd(&lh[(N_USERS + i0.z) >> 10], 1);
            atomicAdd(&lh[(N_USERS + i0.w) >> 10], 1);
            atomicAdd(&lh[(N_USERS + i1.x) >> 10], 1);
            atomicAdd(&lh[(N_USERS + i1.y) >> 10], 1);
            atomicAdd(&lh[(N_USERS + i1.z) >> 10], 1);
            atomicAdd(&lh[(N_USERS + i1.w) >> 10], 1);
        }
        __syncthreads();
        for (int k = threadIdx.x; k < NPART; k += 256) {
            int v = lh[k];
            if (v) atomicAdd(&partTotals[k], v);   // fire-and-forget
        }
    } else if (bid < HA + CB) {
        // f32 -> bf16 convert, 8 floats/thread; boundary (12.8M) % 8 == 0.
        int j = (bid - HA) * 256 + threadIdx.x;      // [0, 2.4M)
        int f4 = j * 2;
        const int NU4 = N_USERS * DIM / 4;           // 3.2M
        float4 a, b;
        if (f4 < NU4) { a = uf4[f4]; b = uf4[f4 + 1]; }
        else          { a = if4[f4 - NU4]; b = if4[f4 - NU4 + 1]; }
        uint2 pa = pack4(a), pb = pack4(b);
        *reinterpret_cast<uint4*>(F0 + (size_t)j * 8) =
            make_uint4(pa.x, pa.y, pb.x, pb.y);
    } else {
        // out = 0.25 * h0 at gathered rows (f32 inputs, no quantization)
        int idx = (bid - HA - CB) * 256 + threadIdx.x;
        int row = idx >> 4;
        if (row >= NOUT) return;
        int d4 = (idx & 15) << 2;
        int seg = row >> 13;
        int b = row & (BATCH - 1);
        const float* src;
        if (seg == 0)      src = u_feat + (size_t)users[b] * DIM;
        else if (seg == 1) src = i_feat + (size_t)pos[b]   * DIM;
        else               src = i_feat + (size_t)neg[b]   * DIM;
        float4 v = *reinterpret_cast<const float4*>(src + d4);
        v.x *= 0.25f; v.y *= 0.25f; v.z *= 0.25f; v.w *= 0.25f;
        *reinterpret_cast<float4*>(out + (size_t)row * DIM + d4) = v;
    }
}

// ---------------- S: scan partition totals ----------------
__global__ void part_scan_kernel(const int* __restrict__ partTotals,
                                 int* __restrict__ partStart,
                                 int* __restrict__ gcur)
{
    __shared__ int s[512];
    int t = threadIdx.x;
    s[t] = (t < NPART) ? partTotals[t] : 0;
    __syncthreads();
    for (int off = 1; off < 512; off <<= 1) {
        int x = (t >= off) ? s[t - off] : 0;
        __syncthreads();
        s[t] += x;
        __syncthreads();
    }
    if (t < NPART) {
        int st = (t == 0) ? 0 : s[t - 1];
        partStart[t] = st;
        gcur[t] = st;
    }
    if (t == NPART) partStart[NPART] = s[NPART - 1];   // == 2*N_EDGES
}

// ---------------- B: partition scatter ----------------
// record meta = (bucket & 1023) | (col << 10);  col < 2^19, total 29 bits.
__global__ void partition_kernel(const int* __restrict__ eu,
                                 const int* __restrict__ ei,
                                 const float* __restrict__ w,
                                 int* __restrict__ gcur,
                                 uint2* __restrict__ partBuf)
{
    __shared__ int lh[NPART];
    __shared__ int lcur[NPART];
    int bid = blockIdx.x, t = threadIdx.x;
    for (int k = t; k < NPART; k += 256) lh[k] = 0;
    __syncthreads();
    int e0 = (bid * 256 + t) * 8;
    bool act = e0 < N_EDGES;
    int4 u0, u1, i0, i1;
    if (act) {
        u0 = *reinterpret_cast<const int4*>(eu + e0);
        u1 = *reinterpret_cast<const int4*>(eu + e0 + 4);
        i0 = *reinterpret_cast<const int4*>(ei + e0);
        i1 = *reinterpret_cast<const int4*>(ei + e0 + 4);
        atomicAdd(&lh[u0.x >> 10], 1);
        atomicAdd(&lh[u0.y >> 10], 1);
        atomicAdd(&lh[u0.z >> 10], 1);
        atomicAdd(&lh[u0.w >> 10], 1);
        atomicAdd(&lh[u1.x >> 10], 1);
        atomicAdd(&lh[u1.y >> 10], 1);
        atomicAdd(&lh[u1.z >> 10], 1);
        atomicAdd(&lh[u1.w >> 10], 1);
        atomicAdd(&lh[(N_USERS + i0.x) >> 10], 1);
        atomicAdd(&lh[(N_USERS + i0.y) >> 10], 1);
        atomicAdd(&lh[(N_USERS + i0.z) >> 10], 1);
        atomicAdd(&lh[(N_USERS + i0.w) >> 10], 1);
        atomicAdd(&lh[(N_USERS + i1.x) >> 10], 1);
        atomicAdd(&lh[(N_USERS + i1.y) >> 10], 1);
        atomicAdd(&lh[(N_USERS + i1.z) >> 10], 1);
        atomicAdd(&lh[(N_USERS + i1.w) >> 10], 1);
    }
    __syncthreads();
    // reserve: one returning atomic per (block, nonempty partition)
    for (int k = t; k < NPART; k += 256) {
        int v = lh[k];
        lcur[k] = v ? atomicAdd(&gcur[k], v) : 0;
    }
    __syncthreads();
    if (act) {
        float4 wa = *reinterpret_cast<const float4*>(w + e0);
        float4 wb = *reinterpret_cast<const float4*>(w + e0 + 4);
        int us[8] = {u0.x, u0.y, u0.z, u0.w, u1.x, u1.y, u1.z, u1.w};
        int is[8] = {i0.x, i0.y, i0.z, i0.w, i1.x, i1.y, i1.z, i1.w};
        float ws[8] = {wa.x, wa.y, wa.z, wa.w, wb.x, wb.y, wb.z, wb.w};
        #pragma unroll
        for (int j = 0; j < 8; ++j) {
            int bu = us[j];
            int bi = N_USERS + is[j];
            unsigned wbits = __float_as_uint(ws[j]);
            int su = atomicAdd(&lcur[bu >> 10], 1);    // LDS
            partBuf[su] = make_uint2((unsigned)(bu & 1023) | ((unsigned)bi << 10), wbits);
            int si = atomicAdd(&lcur[bi >> 10], 1);    // LDS
            partBuf[si] = make_uint2((unsigned)(bi & 1023) | ((unsigned)bu << 10), wbits);
        }
    }
}

// ---------------- C: per-partition CSR build (rp + entries) ----------------
__global__ void build_csr_kernel(const int* __restrict__ partStart,
                                 const uint2* __restrict__ partBuf,
                                 int* __restrict__ rp,
                                 int2* __restrict__ entries)
{
    __shared__ int h[PLOCAL];
    __shared__ int cur[PLOCAL];
    __shared__ int s[256];
    int p = blockIdx.x, t = threadIdx.x;
    int base = partStart[p], end = partStart[p + 1];
    h[t * 4 + 0] = 0; h[t * 4 + 1] = 0; h[t * 4 + 2] = 0; h[t * 4 + 3] = 0;
    __syncthreads();
    for (int r = base + t; r < end; r += 256)
        atomicAdd(&h[partBuf[r].x & 1023], 1);
    __syncthreads();
    int h0 = h[t * 4], h1 = h[t * 4 + 1], h2 = h[t * 4 + 2], h3 = h[t * 4 + 3];
    s[t] = h0 + h1 + h2 + h3;
    __syncthreads();
    for (int off = 1; off < 256; off <<= 1) {
        int x = (t >= off) ? s[t - off] : 0;
        __syncthreads();
        s[t] += x;
        __syncthreads();
    }
    int b0 = base + ((t == 0) ? 0 : s[t - 1]);
    cur[t * 4 + 0] = b0;
    cur[t * 4 + 1] = b0 + h0;
    cur[t * 4 + 2] = b0 + h0 + h1;
    cur[t * 4 + 3] = b0 + h0 + h1 + h2;
    // write rp slice (cur values BEFORE scatter mutates them)
    int gb = p * PLOCAL + t * 4;
    #pragma unroll
    for (int k = 0; k < 4; ++k)
        if (gb + k <= NTOT) rp[gb + k] = cur[t * 4 + k];
    __syncthreads();
    for (int r = base + t; r < end; r += 256) {
        uint2 rec = partBuf[r];
        int b = rec.x & 1023;
        int col = rec.x >> 10;
        int slot = atomicAdd(&cur[b], 1);              // LDS
        entries[slot] = make_int2(col, (int)rec.y);
    }
}

// ---------------- agg core (4 rows/wave, 8-deep unroll) ----------------
#define GATH(idx, acc)                                                        \
    {                                                                         \
        int c = __shfl(e.x, qb + (idx));                                      \
        float ww = __int_as_float(__shfl(e.y, qb + (idx)));                   \
        uint2 v = *reinterpret_cast<const uint2*>(                            \
            src + (size_t)c * DIM + l16 * 4);                                 \
        fma4(acc, v, ww);                                                     \
    }

__device__ __forceinline__ void agg_row(int row, int l16, int quad,
                                        const int* __restrict__ rp,
                                        const int2* __restrict__ entries,
                                        const unsigned short* __restrict__ src,
                                        float4& s)
{
    int beg = rp[row];
    int end = rp[row + 1];
    int cnt = end - beg;
    int qb = quad << 4;
    float4 a0 = {0,0,0,0}, a1 = {0,0,0,0}, a2 = {0,0,0,0}, a3 = {0,0,0,0};
    for (int base = 0; base < cnt; base += 16) {
        int rem = min(16, cnt - base);
        int2 e = make_int2(0, 0);
        if (l16 < rem) e = entries[beg + base + l16];
        int j = 0;
        for (; j + 7 < rem; j += 8) {
            GATH(j + 0, a0) GATH(j + 1, a1) GATH(j + 2, a2) GATH(j + 3, a3)
            GATH(j + 4, a0) GATH(j + 5, a1) GATH(j + 6, a2) GATH(j + 7, a3)
        }
        if (j + 3 < rem) {
            GATH(j + 0, a0) GATH(j + 1, a1) GATH(j + 2, a2) GATH(j + 3, a3)
            j += 4;
        }
        if (j + 1 < rem) {
            GATH(j + 0, a0) GATH(j + 1, a1)
            j += 2;
        }
        if (j < rem) GATH(j, a2)
    }
    s.x = (a0.x + a1.x) + (a2.x + a3.x);
    s.y = (a0.y + a1.y) + (a2.y + a3.y);
    s.z = (a0.z + a1.z) + (a2.z + a3.z);
    s.w = (a0.w + a1.w) + (a2.w + a3.w);
}

// ---------------- layer 1 (all rows) + flag scatter ----------------
__global__ void agg1_flag_kernel(const int* __restrict__ rp,
                                 const int2* __restrict__ entries,
                                 const unsigned short* __restrict__ F0,
                                 unsigned short* __restrict__ H1,
                                 const int* __restrict__ users,
                                 const int* __restrict__ pos,
                                 const int* __restrict__ neg,
                                 int* __restrict__ flags)
{
    int bid = blockIdx.x;
    if (bid < AB) {
        int gid = bid * 256 + threadIdx.x;
        int lane = gid & 63;
        int quad = lane >> 4;
        int l16 = lane & 15;
        int row = (gid >> 6) * 4 + quad;
        if (row >= NTOT) return;
        float4 s;
        agg_row(row, l16, quad, rp, entries, F0, s);
        *reinterpret_cast<uint2*>(H1 + (size_t)row * DIM + l16 * 4) = pack4(s);
    } else {
        int t = (bid - AB) * 256 + threadIdx.x;
        if (t >= NOUT) return;
        int bucket = out_bucket(t, users, pos, neg);
        flags[bucket] = 1;
        int beg = rp[bucket], end = rp[bucket + 1];
        for (int k = beg; k < end; ++k)
            flags[entries[k].x] = 1;
    }
}

// ---------------- compact flags -> row list ----------------
__global__ void compact_kernel(const int* __restrict__ flags,
                               int* __restrict__ list,
                               int* __restrict__ count)
{
    int t = blockIdx.x * blockDim.x + threadIdx.x;
    int idx = t * 4;
    if (idx >= NTOT) return;
    int4 f = *reinterpret_cast<const int4*>(flags + idx);
    int loc[4]; int k = 0;
    if (f.x) loc[k++] = idx;
    if (f.y) loc[k++] = idx + 1;
    if (f.z) loc[k++] = idx + 2;
    if (f.w) loc[k++] = idx + 3;
    if (k) {
        int base = atomicAdd(count, k);
        for (int m = 0; m < k; ++m) list[base + m] = loc[m];
    }
}

// ---------------- layer 2 (listed rows only) + out += 0.25*H1 ----------------
__global__ void agg2_add1_kernel(const int* __restrict__ rp,
                                 const int2* __restrict__ entries,
                                 const unsigned short* __restrict__ H1,
                                 unsigned short* __restrict__ H2,
                                 const int* __restrict__ list,
                                 const int* __restrict__ count,
                                 const int* __restrict__ users,
                                 const int* __restrict__ pos,
                                 const int* __restrict__ neg,
                                 float* __restrict__ out)
{
    int bid = blockIdx.x;
    if (bid < AB) {
        int gid = bid * 256 + threadIdx.x;
        int lane = gid & 63;
        int quad = lane >> 4;
        int l16 = lane & 15;
        int idx4 = (gid >> 6) * 4 + quad;
        int n = *count;
        if (idx4 >= n) return;
        int row = list[idx4];
        float4 s;
        agg_row(row, l16, quad, rp, entries, H1, s);
        *reinterpret_cast<uint2*>(H2 + (size_t)row * DIM + l16 * 4) = pack4(s);
    } else {
        int idx = (bid - AB) * 256 + threadIdx.x;
        int row = idx >> 4;
        if (row >= NOUT) return;
        int d4 = (idx & 15) << 2;
        int bucket = out_bucket(row, users, pos, neg);
        uint2 v = *reinterpret_cast<const uint2*>(H1 + (size_t)bucket * DIM + d4);
        float* op = out + (size_t)row * DIM + d4;
        float4 o = *reinterpret_cast<const float4*>(op);
        o.x += 0.25f * __uint_as_float(v.x << 16);
        o.y += 0.25f * __uint_as_float(v.x & 0xffff0000u);
        o.z += 0.25f * __uint_as_float(v.y << 16);
        o.w += 0.25f * __uint_as_float(v.y & 0xffff0000u);
        *reinterpret_cast<float4*>(op) = o;
    }
}

// ---------------- layer 3 at output rows, H2 add fused IN-THREAD ----------------
__global__ void aggout_add2_kernel(const int* __restrict__ rp,
                                   const int2* __restrict__ entries,
                                   const unsigned short* __restrict__ H2,
                                   const int* __restrict__ users,
                                   const int* __restrict__ pos,
                                   const int* __restrict__ neg,
                                   float* __restrict__ out)
{
    int gid = blockIdx.x * 256 + threadIdx.x;
    int lane = gid & 63;
    int quad = lane >> 4;
    int l16 = lane & 15;
    int orow = (gid >> 6) * 4 + quad;
    if (orow >= NOUT) return;
    int bucket = out_bucket(orow, users, pos, neg);
    float4 s;
    agg_row(bucket, l16, quad, rp, entries, H2, s);
    uint2 v = *reinterpret_cast<const uint2*>(H2 + (size_t)bucket * DIM + l16 * 4);
    s.x += __uint_as_float(v.x << 16);
    s.y += __uint_as_float(v.x & 0xffff0000u);
    s.z += __uint_as_float(v.y << 16);
    s.w += __uint_as_float(v.y & 0xffff0000u);
    float* op = out + (size_t)orow * DIM + l16 * 4;
    float4 o = *reinterpret_cast<const float4*>(op);
    o.x += 0.25f * s.x; o.y += 0.25f * s.y;
    o.z += 0.25f * s.z; o.w += 0.25f * s.w;
    *reinterpret_cast<float4*>(op) = o;
}

extern "C" void kernel_launch(void* const* d_in, const int* in_sizes, int n_in,
                              void* d_out, int out_size, void* d_ws, size_t ws_size,
                              hipStream_t stream)
{
    const float* user_feat = (const float*)d_in[0];
    const float* item_feat = (const float*)d_in[1];
    const int*   eu        = (const int*)d_in[2];
    const int*   ei        = (const int*)d_in[3];
    const float* norm      = (const float*)d_in[4];
    const int*   users     = (const int*)d_in[5];
    const int*   pos       = (const int*)d_in[6];
    const int*   neg       = (const int*)d_in[7];
    float* out = (float*)d_out;

    auto align256 = [](size_t x) { return (x + 255) & ~(size_t)255; };
    const size_t hBytes = (size_t)NTOT * DIM * sizeof(unsigned short);  // 38.4 MB

    char* p = (char*)d_ws;
    unsigned short* F0 = (unsigned short*)p; p += align256(hBytes);
    unsigned short* H1 = (unsigned short*)p; p += align256(hBytes);
    unsigned short* H2 = (unsigned short*)p; p += align256(hBytes);
    // memset region: partTotals(512 pad) | flags(NTOT) | count(16 pad)
    int* partTotals = (int*)p; p += align256((size_t)(512 + NTOT + 16) * 4);
    int* flags = partTotals + 512;
    int* count = flags + NTOT;
    int*  partStart = (int*)p;  p += align256(512 * 4);
    int*  gcur      = (int*)p;  p += align256(512 * 4);
    int*  rp        = (int*)p;  p += align256((size_t)(NTOT + 1) * 4);
    uint2* partBuf  = (uint2*)p; p += align256((size_t)2 * N_EDGES * 8);
    int*  list      = (int*)p;  p += align256((size_t)NTOT * 4);
    int2* entries   = (int2*)p; p += align256((size_t)2 * N_EDGES * 8);
    // total ~150 MB

    hipMemsetAsync(partTotals, 0, (size_t)(512 + NTOT + 16) * 4, stream);

    // A: partition hist + convert + out_h0
    fused_pre_kernel<<<HA + CB + OB, 256, 0, stream>>>(
        eu, ei, partTotals,
        (const float4*)user_feat, (const float4*)item_feat, F0,
        user_feat, item_feat, users, pos, neg, out);

    // S: scan partition totals
    part_scan_kernel<<<1, 512, 0, stream>>>(partTotals, partStart, gcur);

    // B: partition scatter
    partition_kernel<<<HA, 256, 0, stream>>>(eu, ei, norm, gcur, partBuf);

    // C: per-partition CSR build (writes rp + entries)
    build_csr_kernel<<<NPART, 256, 0, stream>>>(partStart, partBuf, rp, entries);

    // layer 1 (all rows) + flag scatter for needed-H2 set
    agg1_flag_kernel<<<AB + FB, 256, 0, stream>>>(
        rp, entries, F0, H1, users, pos, neg, flags);

    compact_kernel<<<(NTOT / 4 + 255) / 256, 256, 0, stream>>>(flags, list, count);

    // layer 2 (listed rows) + out += 0.25*H1
    agg2_add1_kernel<<<AB + OB, 256, 0, stream>>>(
        rp, entries, H1, H2, list, count, users, pos, neg, out);

    // layer 3 at output rows with in-thread H2 add
    aggout_add2_kernel<<<NOUT / 16, 256, 0, stream>>>(
        rp, entries, H2, users, pos, neg, out);
}